// Round 1
// baseline (16173.598 us; speedup 1.0000x reference)
//
#include <hip/hip_runtime.h>
#include <cstdint>
#include <cstddef>

#define NU 100000
#define NI 50000
#define DIMK 64
#define NNZP 2000000
#define NNZN 1000000
#define BQ 8192

// ---------------------------------------------------------------------------
// SpMM (COO, both directions in one pass):
//   Zu[row] += v * Ei[col]
//   Zi[col] += v * Eu[row]
// 16 threads per nnz, float4 per thread, hardware fp32 atomics.
// ---------------------------------------------------------------------------
__global__ __launch_bounds__(256) void spmm_pair(
    const int* __restrict__ rows, const int* __restrict__ cols,
    const float* __restrict__ vals, int nnz,
    const float* __restrict__ Eu, const float* __restrict__ Ei,
    float* __restrict__ Zu, float* __restrict__ Zi)
{
    long long t = (long long)blockIdx.x * 256 + threadIdx.x;
    int n = (int)(t >> 4);
    if (n >= nnz) return;
    int e = ((int)t & 15) * 4;
    int r = rows[n];
    int c = cols[n];
    float v = vals[n];
    float4 xi = *(const float4*)(Ei + (size_t)c * DIMK + e);
    float4 xu = *(const float4*)(Eu + (size_t)r * DIMK + e);
    float* zu = Zu + (size_t)r * DIMK + e;
    float* zi = Zi + (size_t)c * DIMK + e;
    unsafeAtomicAdd(zu + 0, v * xi.x);
    unsafeAtomicAdd(zu + 1, v * xi.y);
    unsafeAtomicAdd(zu + 2, v * xi.z);
    unsafeAtomicAdd(zu + 3, v * xi.w);
    unsafeAtomicAdd(zi + 0, v * xu.x);
    unsafeAtomicAdd(zi + 1, v * xu.y);
    unsafeAtomicAdd(zi + 2, v * xu.z);
    unsafeAtomicAdd(zi + 3, v * xu.w);
}

// ---------------------------------------------------------------------------
// Fused 5-term linear + leaky-relu, writes result IN PLACE into Zp buffer.
//   m[r,j] = sum_k E[r,k]W0[j,k] + Zp[r,k]W1[j,k] + (Zp*E)[r,k]W2[j,k]
//                 + Zn[r,k]W3[j,k] + (Zn*E)[r,k]W4[j,k]  + sum_t b_t[j]
//   out[r,j] = m > 0 ? m : 0.2*m
// Block: 256 threads = 64 j-lanes x 4 row-groups; 16 rows/block.
// W (5x64x64 fp32 = 80KB) staged transposed [t][k][j] in LDS (2 blocks/CU).
// ---------------------------------------------------------------------------
__global__ __launch_bounds__(256) void linear_fuse(
    const float* __restrict__ Xe, float* __restrict__ Zp,
    const float* __restrict__ Zn,
    const float* __restrict__ W, const float* __restrict__ b, int N)
{
    __shared__ float Ws[5 * 64 * 64];  // [t][k][j], 80 KiB
    int tid = threadIdx.x;

    // stage W transposed: element W[t][j][k] -> Ws[t*4096 + k*64 + j]
    for (int g = tid; g < 5120; g += 256) {
        int j0 = g & 63;
        int kq = (g >> 6) & 15;
        int t  = g >> 10;
        float4 w = *(const float4*)(W + (size_t)t * 4096 + (size_t)j0 * 64 + kq * 4);
        int base = t * 4096 + kq * 4 * 64 + j0;
        Ws[base +   0] = w.x;
        Ws[base +  64] = w.y;
        Ws[base + 128] = w.z;
        Ws[base + 192] = w.w;
    }

    int j  = tid & 63;
    int rq = tid >> 6;
    float bsum = b[j] + b[64 + j] + b[128 + j] + b[192 + j] + b[256 + j];
    __syncthreads();

    int r_base = blockIdx.x * 16 + rq * 4;
    int rr[4];
#pragma unroll
    for (int i = 0; i < 4; i++) {
        int r = r_base + i;
        rr[i] = (r < N) ? r : (N - 1);  // clamp for loads; stores are guarded
    }

    float acc[4] = {bsum, bsum, bsum, bsum};

    for (int k4 = 0; k4 < 64; k4 += 4) {
        float4 e4[4], p4[4], n4[4];
#pragma unroll
        for (int i = 0; i < 4; i++) {
            e4[i] = *(const float4*)(Xe + (size_t)rr[i] * 64 + k4);
            p4[i] = *(const float4*)(Zp + (size_t)rr[i] * 64 + k4);
            n4[i] = *(const float4*)(Zn + (size_t)rr[i] * 64 + k4);
        }
#pragma unroll
        for (int q = 0; q < 4; q++) {
            int k = k4 + q;
            float w0 = Ws[            k * 64 + j];
            float w1 = Ws[ 4096 +     k * 64 + j];
            float w2 = Ws[ 8192 +     k * 64 + j];
            float w3 = Ws[12288 +     k * 64 + j];
            float w4 = Ws[16384 +     k * 64 + j];
#pragma unroll
            for (int i = 0; i < 4; i++) {
                float e  = ((const float*)&e4[i])[q];
                float zp = ((const float*)&p4[i])[q];
                float zn = ((const float*)&n4[i])[q];
                acc[i] = fmaf(e,      w0, acc[i]);
                acc[i] = fmaf(zp,     w1, acc[i]);
                acc[i] = fmaf(zp * e, w2, acc[i]);
                acc[i] = fmaf(zn,     w3, acc[i]);
                acc[i] = fmaf(zn * e, w4, acc[i]);
            }
        }
    }

    __syncthreads();  // all reads of Zp rows in this block done before overwrite
#pragma unroll
    for (int i = 0; i < 4; i++) {
        int r = r_base + i;
        if (r < N) {
            float m = acc[i];
            Zp[(size_t)r * 64 + j] = (m > 0.f) ? m : 0.2f * m;
        }
    }
}

// ---------------------------------------------------------------------------
// Final gather: normalize u rows, logits, partial loss per block.
// ---------------------------------------------------------------------------
__global__ __launch_bounds__(256) void finalize_kernel(
    const float* __restrict__ Eu, const float* __restrict__ Ei,
    const int* __restrict__ uids, const int* __restrict__ iids,
    const float* __restrict__ labels,
    float* __restrict__ out, float* __restrict__ partials)
{
    int bidx = blockIdx.x * 256 + threadIdx.x;
    float part = 0.f;
    if (bidx < BQ) {
        const float4* u4 = (const float4*)(Eu + (size_t)uids[bidx] * 64);
        const float4* i4 = (const float4*)(Ei + (size_t)iids[bidx] * 64);
        float nrm = 0.f, dot = 0.f, regi = 0.f;
#pragma unroll
        for (int q = 0; q < 16; q++) {
            float4 u = u4[q], w = i4[q];
            nrm  += u.x * u.x + u.y * u.y + u.z * u.z + u.w * u.w;
            dot  += u.x * w.x + u.y * w.y + u.z * w.z + u.w * w.w;
            regi += w.x * w.x + w.y * w.y + w.z * w.z + w.w * w.w;
        }
        float inv   = 1.f / fmaxf(sqrtf(nrm), 1e-12f);
        float logit = dot * inv;
        out[1 + bidx] = logit;
        float regu = nrm * inv * inv;
        float y  = labels[bidx];
        float sp = fmaxf(logit, 0.f) + log1pf(expf(-fabsf(logit)));
        part = (sp - logit * y) * (1.f / (float)BQ) + 1e-6f * (regu + regi);
    }
    __shared__ float red[256];
    red[threadIdx.x] = part;
    __syncthreads();
    for (int s = 128; s > 0; s >>= 1) {
        if (threadIdx.x < s) red[threadIdx.x] += red[threadIdx.x + s];
        __syncthreads();
    }
    if (threadIdx.x == 0) partials[blockIdx.x] = red[0];
}

__global__ void reduce_loss(const float* __restrict__ partials, float* __restrict__ out)
{
    if (threadIdx.x == 0) {
        float s = 0.f;
        for (int i = 0; i < 32; i++) s += partials[i];
        out[0] = s;
    }
}

// ---------------------------------------------------------------------------
extern "C" void kernel_launch(void* const* d_in, const int* in_sizes, int n_in,
                              void* d_out, int out_size, void* d_ws, size_t ws_size,
                              hipStream_t stream)
{
    const int*   pos_rows = (const int*)d_in[0];
    const int*   pos_cols = (const int*)d_in[1];
    const float* pos_vals = (const float*)d_in[2];
    const int*   neg_rows = (const int*)d_in[3];
    const int*   neg_cols = (const int*)d_in[4];
    const float* neg_vals = (const float*)d_in[5];
    const int*   uids     = (const int*)d_in[6];
    const int*   iids     = (const int*)d_in[7];
    const float* labels   = (const float*)d_in[8];
    const float* E_u_0    = (const float*)d_in[9];
    const float* E_i_0    = (const float*)d_in[10];
    const float* W_u      = (const float*)d_in[11];
    const float* b_u      = (const float*)d_in[12];
    const float* W_i      = (const float*)d_in[13];
    const float* b_i      = (const float*)d_in[14];

    float* ws = (float*)d_ws;
    const size_t SU = (size_t)NU * DIMK;  // 6.4M floats
    const size_t SI = (size_t)NI * DIMK;  // 3.2M floats
    float* Ub[3] = { ws,           ws + SU,      ws + 2 * SU };
    float* Ib[3] = { ws + 3 * SU,  ws + 3 * SU + SI, ws + 3 * SU + 2 * SI };
    float* partials = ws + 3 * SU + 3 * SI;  // 32 floats

    const float* Eu_cur = E_u_0;
    const float* Ei_cur = E_i_0;

    for (int l = 0; l < 3; l++) {
        float* Zup = Ub[l];
        float* Zun = Ub[(l + 1) % 3];
        float* Zip = Ib[l];
        float* Zin = Ib[(l + 1) % 3];
        hipMemsetAsync(Zup, 0, SU * sizeof(float), stream);
        hipMemsetAsync(Zun, 0, SU * sizeof(float), stream);
        hipMemsetAsync(Zip, 0, SI * sizeof(float), stream);
        hipMemsetAsync(Zin, 0, SI * sizeof(float), stream);

        spmm_pair<<<(NNZP * 16) / 256, 256, 0, stream>>>(
            pos_rows, pos_cols, pos_vals, NNZP, Eu_cur, Ei_cur, Zup, Zip);
        spmm_pair<<<(NNZN * 16) / 256, 256, 0, stream>>>(
            neg_rows, neg_cols, neg_vals, NNZN, Eu_cur, Ei_cur, Zun, Zin);

        linear_fuse<<<(NU + 15) / 16, 256, 0, stream>>>(
            Eu_cur, Zup, Zun, W_u + (size_t)l * 5 * 64 * 64, b_u + (size_t)l * 5 * 64, NU);
        linear_fuse<<<(NI + 15) / 16, 256, 0, stream>>>(
            Ei_cur, Zip, Zin, W_i + (size_t)l * 5 * 64 * 64, b_i + (size_t)l * 5 * 64, NI);

        Eu_cur = Zup;
        Ei_cur = Zip;
    }

    finalize_kernel<<<BQ / 256, 256, 0, stream>>>(
        Eu_cur, Ei_cur, uids, iids, labels, (float*)d_out, partials);
    reduce_loss<<<1, 64, 0, stream>>>(partials, (float*)d_out);
}

// Round 2
// 2980.667 us; speedup vs baseline: 5.4262x; 5.4262x over previous
//
#include <hip/hip_runtime.h>
#include <cstdint>
#include <cstddef>

#define NU 100000
#define NI 50000
#define DIMK 64
#define NNZP 2000000
#define NNZN 1000000
#define BQ 8192

// ---------------------------------------------------------------------------
// Histogram both key directions in one pass over the COO arrays.
// ---------------------------------------------------------------------------
__global__ __launch_bounds__(256) void hist2(
    const int* __restrict__ rows, const int* __restrict__ cols, int nnz,
    int* __restrict__ cntR, int* __restrict__ cntC)
{
    int i = blockIdx.x * 256 + threadIdx.x;
    if (i >= nnz) return;
    atomicAdd(&cntR[rows[i]], 1);
    atomicAdd(&cntC[cols[i]], 1);
}

// ---------------------------------------------------------------------------
// Exclusive scan of 4 count arrays (one block each). cnt[] is rewritten to
// the running start offsets ("cur" for the scatter); ptr[] gets starts + total.
// ---------------------------------------------------------------------------
__global__ __launch_bounds__(1024) void exscan4(
    int* c0, int* p0, int n0, int* c1, int* p1, int n1,
    int* c2, int* p2, int n2, int* c3, int* p3, int n3)
{
    int* cnt; int* ptr; int n;
    switch (blockIdx.x) {
        case 0:  cnt = c0; ptr = p0; n = n0; break;
        case 1:  cnt = c1; ptr = p1; n = n1; break;
        case 2:  cnt = c2; ptr = p2; n = n2; break;
        default: cnt = c3; ptr = p3; n = n3; break;
    }
    __shared__ int ssum[1024];
    int t = threadIdx.x;
    int chunk = (n + 1023) >> 10;
    int start = t * chunk;
    int end   = min(start + chunk, n);
    int s = 0;
    for (int i = start; i < end; i++) s += cnt[i];
    ssum[t] = s;
    __syncthreads();
    for (int off = 1; off < 1024; off <<= 1) {
        int v = (t >= off) ? ssum[t - off] : 0;
        __syncthreads();
        ssum[t] += v;
        __syncthreads();
    }
    int base = (t > 0) ? ssum[t - 1] : 0;
    for (int i = start; i < end; i++) {
        int c = cnt[i];
        ptr[i] = base;
        cnt[i] = base;   // becomes scatter cursor
        base += c;
    }
    if (t == 0) ptr[n] = ssum[1023];
}

// ---------------------------------------------------------------------------
// Scatter into both sorted edge lists: byR[(col,val)] sorted by row,
// byC[(row,val)] sorted by col.
// ---------------------------------------------------------------------------
__global__ __launch_bounds__(256) void scatter2(
    const int* __restrict__ rows, const int* __restrict__ cols,
    const float* __restrict__ vals, int nnz,
    int* __restrict__ curR, int* __restrict__ curC,
    int2* __restrict__ byR, int2* __restrict__ byC)
{
    int i = blockIdx.x * 256 + threadIdx.x;
    if (i >= nnz) return;
    int r = rows[i], c = cols[i];
    int vb = __float_as_int(vals[i]);
    int p = atomicAdd(&curR[r], 1);
    byR[p] = make_int2(c, vb);
    int q = atomicAdd(&curC[c], 1);
    byC[q] = make_int2(r, vb);
}

// ---------------------------------------------------------------------------
// Gather SpMM: one wave per output row, lane k owns element k.
// Edges batch-loaded 64-wide, broadcast via shfl; no atomics, full-row store.
// ---------------------------------------------------------------------------
__global__ __launch_bounds__(256) void spmm_gather(
    const int* __restrict__ ptr, const int2* __restrict__ edges,
    const float* __restrict__ X, float* __restrict__ Z, int nrows)
{
    int wid  = (blockIdx.x * 256 + threadIdx.x) >> 6;
    int lane = threadIdx.x & 63;
    if (wid >= nrows) return;
    int beg = ptr[wid], end = ptr[wid + 1];
    float acc = 0.f;
    for (int e0 = beg; e0 < end; e0 += 64) {
        int2 ed = make_int2(0, 0);
        if (e0 + lane < end) ed = edges[e0 + lane];
        int nb = min(64, end - e0);
#pragma unroll 4
        for (int j = 0; j < nb; j++) {
            int   col = __shfl(ed.x, j, 64);
            float v   = __int_as_float(__shfl(ed.y, j, 64));
            acc = fmaf(v, X[(size_t)col * DIMK + lane], acc);
        }
    }
    Z[(size_t)wid * DIMK + lane] = acc;
}

// ---------------------------------------------------------------------------
// Fused 5-term linear + leaky-relu, in place into Zp. (unchanged from R0)
// ---------------------------------------------------------------------------
__global__ __launch_bounds__(256) void linear_fuse(
    const float* __restrict__ Xe, float* __restrict__ Zp,
    const float* __restrict__ Zn,
    const float* __restrict__ W, const float* __restrict__ b, int N)
{
    __shared__ float Ws[5 * 64 * 64];  // [t][k][j], 80 KiB
    int tid = threadIdx.x;

    for (int g = tid; g < 5120; g += 256) {
        int j0 = g & 63;
        int kq = (g >> 6) & 15;
        int t  = g >> 10;
        float4 w = *(const float4*)(W + (size_t)t * 4096 + (size_t)j0 * 64 + kq * 4);
        int base = t * 4096 + kq * 4 * 64 + j0;
        Ws[base +   0] = w.x;
        Ws[base +  64] = w.y;
        Ws[base + 128] = w.z;
        Ws[base + 192] = w.w;
    }

    int j  = tid & 63;
    int rq = tid >> 6;
    float bsum = b[j] + b[64 + j] + b[128 + j] + b[192 + j] + b[256 + j];
    __syncthreads();

    int r_base = blockIdx.x * 16 + rq * 4;
    int rr[4];
#pragma unroll
    for (int i = 0; i < 4; i++) {
        int r = r_base + i;
        rr[i] = (r < N) ? r : (N - 1);
    }

    float acc[4] = {bsum, bsum, bsum, bsum};

    for (int k4 = 0; k4 < 64; k4 += 4) {
        float4 e4[4], p4[4], n4[4];
#pragma unroll
        for (int i = 0; i < 4; i++) {
            e4[i] = *(const float4*)(Xe + (size_t)rr[i] * 64 + k4);
            p4[i] = *(const float4*)(Zp + (size_t)rr[i] * 64 + k4);
            n4[i] = *(const float4*)(Zn + (size_t)rr[i] * 64 + k4);
        }
#pragma unroll
        for (int q = 0; q < 4; q++) {
            int k = k4 + q;
            float w0 = Ws[            k * 64 + j];
            float w1 = Ws[ 4096 +     k * 64 + j];
            float w2 = Ws[ 8192 +     k * 64 + j];
            float w3 = Ws[12288 +     k * 64 + j];
            float w4 = Ws[16384 +     k * 64 + j];
#pragma unroll
            for (int i = 0; i < 4; i++) {
                float e  = ((const float*)&e4[i])[q];
                float zp = ((const float*)&p4[i])[q];
                float zn = ((const float*)&n4[i])[q];
                acc[i] = fmaf(e,      w0, acc[i]);
                acc[i] = fmaf(zp,     w1, acc[i]);
                acc[i] = fmaf(zp * e, w2, acc[i]);
                acc[i] = fmaf(zn,     w3, acc[i]);
                acc[i] = fmaf(zn * e, w4, acc[i]);
            }
        }
    }

    __syncthreads();
#pragma unroll
    for (int i = 0; i < 4; i++) {
        int r = r_base + i;
        if (r < N) {
            float m = acc[i];
            Zp[(size_t)r * 64 + j] = (m > 0.f) ? m : 0.2f * m;
        }
    }
}

// ---------------------------------------------------------------------------
// Final gather: normalize u rows, logits, partial loss per block.
// ---------------------------------------------------------------------------
__global__ __launch_bounds__(256) void finalize_kernel(
    const float* __restrict__ Eu, const float* __restrict__ Ei,
    const int* __restrict__ uids, const int* __restrict__ iids,
    const float* __restrict__ labels,
    float* __restrict__ out, float* __restrict__ partials)
{
    int bidx = blockIdx.x * 256 + threadIdx.x;
    float part = 0.f;
    if (bidx < BQ) {
        const float4* u4 = (const float4*)(Eu + (size_t)uids[bidx] * 64);
        const float4* i4 = (const float4*)(Ei + (size_t)iids[bidx] * 64);
        float nrm = 0.f, dot = 0.f, regi = 0.f;
#pragma unroll
        for (int q = 0; q < 16; q++) {
            float4 u = u4[q], w = i4[q];
            nrm  += u.x * u.x + u.y * u.y + u.z * u.z + u.w * u.w;
            dot  += u.x * w.x + u.y * w.y + u.z * w.z + u.w * w.w;
            regi += w.x * w.x + w.y * w.y + w.z * w.z + w.w * w.w;
        }
        float inv   = 1.f / fmaxf(sqrtf(nrm), 1e-12f);
        float logit = dot * inv;
        out[1 + bidx] = logit;
        float regu = nrm * inv * inv;
        float y  = labels[bidx];
        float sp = fmaxf(logit, 0.f) + log1pf(expf(-fabsf(logit)));
        part = (sp - logit * y) * (1.f / (float)BQ) + 1e-6f * (regu + regi);
    }
    __shared__ float red[256];
    red[threadIdx.x] = part;
    __syncthreads();
    for (int s = 128; s > 0; s >>= 1) {
        if (threadIdx.x < s) red[threadIdx.x] += red[threadIdx.x + s];
        __syncthreads();
    }
    if (threadIdx.x == 0) partials[blockIdx.x] = red[0];
}

__global__ void reduce_loss(const float* __restrict__ partials, float* __restrict__ out)
{
    if (threadIdx.x == 0) {
        float s = 0.f;
        for (int i = 0; i < 32; i++) s += partials[i];
        out[0] = s;
    }
}

// ---------------------------------------------------------------------------
extern "C" void kernel_launch(void* const* d_in, const int* in_sizes, int n_in,
                              void* d_out, int out_size, void* d_ws, size_t ws_size,
                              hipStream_t stream)
{
    const int*   pos_rows = (const int*)d_in[0];
    const int*   pos_cols = (const int*)d_in[1];
    const float* pos_vals = (const float*)d_in[2];
    const int*   neg_rows = (const int*)d_in[3];
    const int*   neg_cols = (const int*)d_in[4];
    const float* neg_vals = (const float*)d_in[5];
    const int*   uids     = (const int*)d_in[6];
    const int*   iids     = (const int*)d_in[7];
    const float* labels   = (const float*)d_in[8];
    const float* E_u_0    = (const float*)d_in[9];
    const float* E_i_0    = (const float*)d_in[10];
    const float* W_u      = (const float*)d_in[11];
    const float* b_u      = (const float*)d_in[12];
    const float* W_i      = (const float*)d_in[13];
    const float* b_i      = (const float*)d_in[14];

    char* base = (char*)d_ws;
    size_t off = 0;
    auto alloc = [&](size_t bytes) { char* p = base + off; off += (bytes + 15) & ~(size_t)15; return p; };

    const size_t SU = (size_t)NU * DIMK;
    const size_t SI = (size_t)NI * DIMK;
    float* Ub[3]; float* Ib[3];
    for (int i = 0; i < 3; i++) Ub[i] = (float*)alloc(SU * 4);
    for (int i = 0; i < 3; i++) Ib[i] = (float*)alloc(SI * 4);
    int2* byR_p = (int2*)alloc((size_t)NNZP * 8);
    int2* byC_p = (int2*)alloc((size_t)NNZP * 8);
    int2* byR_n = (int2*)alloc((size_t)NNZN * 8);
    int2* byC_n = (int2*)alloc((size_t)NNZN * 8);
    int* ptr_pr = (int*)alloc((NU + 1) * 4);
    int* ptr_pc = (int*)alloc((NI + 1) * 4);
    int* ptr_nr = (int*)alloc((NU + 1) * 4);
    int* ptr_nc = (int*)alloc((NI + 1) * 4);
    int* cnt_pr = (int*)alloc(NU * 4);
    int* cnt_pc = (int*)alloc(NI * 4);
    int* cnt_nr = (int*)alloc(NU * 4);
    int* cnt_nc = (int*)alloc(NI * 4);
    float* partials = (float*)alloc(32 * 4);

    // ---- CSR/CSC build (once per call) ----
    hipMemsetAsync(cnt_pr, 0, NU * 4, stream);
    hipMemsetAsync(cnt_pc, 0, NI * 4, stream);
    hipMemsetAsync(cnt_nr, 0, NU * 4, stream);
    hipMemsetAsync(cnt_nc, 0, NI * 4, stream);

    hist2<<<(NNZP + 255) / 256, 256, 0, stream>>>(pos_rows, pos_cols, NNZP, cnt_pr, cnt_pc);
    hist2<<<(NNZN + 255) / 256, 256, 0, stream>>>(neg_rows, neg_cols, NNZN, cnt_nr, cnt_nc);

    exscan4<<<4, 1024, 0, stream>>>(cnt_pr, ptr_pr, NU, cnt_pc, ptr_pc, NI,
                                    cnt_nr, ptr_nr, NU, cnt_nc, ptr_nc, NI);

    scatter2<<<(NNZP + 255) / 256, 256, 0, stream>>>(
        pos_rows, pos_cols, pos_vals, NNZP, cnt_pr, cnt_pc, byR_p, byC_p);
    scatter2<<<(NNZN + 255) / 256, 256, 0, stream>>>(
        neg_rows, neg_cols, neg_vals, NNZN, cnt_nr, cnt_nc, byR_n, byC_n);

    // ---- 3 GCN layers ----
    const float* Eu_cur = E_u_0;
    const float* Ei_cur = E_i_0;
    for (int l = 0; l < 3; l++) {
        float* Zup = Ub[l];
        float* Zun = Ub[(l + 1) % 3];
        float* Zip = Ib[l];
        float* Zin = Ib[(l + 1) % 3];

        spmm_gather<<<(NU * 64 + 255) / 256, 256, 0, stream>>>(ptr_pr, byR_p, Ei_cur, Zup, NU);
        spmm_gather<<<(NU * 64 + 255) / 256, 256, 0, stream>>>(ptr_nr, byR_n, Ei_cur, Zun, NU);
        spmm_gather<<<(NI * 64 + 255) / 256, 256, 0, stream>>>(ptr_pc, byC_p, Eu_cur, Zip, NI);
        spmm_gather<<<(NI * 64 + 255) / 256, 256, 0, stream>>>(ptr_nc, byC_n, Eu_cur, Zin, NI);

        linear_fuse<<<(NU + 15) / 16, 256, 0, stream>>>(
            Eu_cur, Zup, Zun, W_u + (size_t)l * 5 * 64 * 64, b_u + (size_t)l * 5 * 64, NU);
        linear_fuse<<<(NI + 15) / 16, 256, 0, stream>>>(
            Ei_cur, Zip, Zin, W_i + (size_t)l * 5 * 64 * 64, b_i + (size_t)l * 5 * 64, NI);

        Eu_cur = Zup;
        Ei_cur = Zip;
    }

    finalize_kernel<<<BQ / 256, 256, 0, stream>>>(
        Eu_cur, Ei_cur, uids, iids, labels, (float*)d_out, partials);
    reduce_loss<<<1, 64, 0, stream>>>(partials, (float*)d_out);
}

// Round 3
// 2684.505 us; speedup vs baseline: 6.0248x; 1.1103x over previous
//
#include <hip/hip_runtime.h>
#include <cstdint>
#include <cstddef>

#define NU 100000
#define NI 50000
#define DIMK 64
#define NNZP 2000000
#define NNZN 1000000
#define BQ 8192
#define NREG 4          // scatter destination regions
#define NBU 6250        // (NU+15)/16 blocks for u-linear
#define NBI 3125        // (NI+15)/16 blocks for i-linear

__device__ inline unsigned short f2bf(float f) {   // RNE fp32 -> bf16
    unsigned u = __float_as_uint(f);
    unsigned r = (u + 0x7fffu + ((u >> 16) & 1u)) >> 16;
    return (unsigned short)r;
}
__device__ inline float bf2f(unsigned short h) {
    return __uint_as_float(((unsigned)h) << 16);
}

// ---------------------------------------------------------------------------
// Fused histogram over pos+neg COO, both key directions.
// ---------------------------------------------------------------------------
__global__ __launch_bounds__(256) void hist_all(
    const int* __restrict__ pr, const int* __restrict__ pc,
    const int* __restrict__ nr, const int* __restrict__ nc,
    int* __restrict__ cnt_pr, int* __restrict__ cnt_pc,
    int* __restrict__ cnt_nr, int* __restrict__ cnt_nc)
{
    int i = blockIdx.x * 256 + threadIdx.x;
    if (i < NNZP) {
        atomicAdd(&cnt_pr[pr[i]], 1);
        atomicAdd(&cnt_pc[pc[i]], 1);
    } else if (i < NNZP + NNZN) {
        int j = i - NNZP;
        atomicAdd(&cnt_nr[nr[j]], 1);
        atomicAdd(&cnt_nc[nc[j]], 1);
    }
}

// ---------------------------------------------------------------------------
// Exclusive scan of 4 count arrays (one block each). cnt[] becomes cursor.
// ---------------------------------------------------------------------------
__global__ __launch_bounds__(1024) void exscan4(
    int* c0, int* p0, int n0, int* c1, int* p1, int n1,
    int* c2, int* p2, int n2, int* c3, int* p3, int n3)
{
    int* cnt; int* ptr; int n;
    switch (blockIdx.x) {
        case 0:  cnt = c0; ptr = p0; n = n0; break;
        case 1:  cnt = c1; ptr = p1; n = n1; break;
        case 2:  cnt = c2; ptr = p2; n = n2; break;
        default: cnt = c3; ptr = p3; n = n3; break;
    }
    __shared__ int ssum[1024];
    int t = threadIdx.x;
    int chunk = (n + 1023) >> 10;
    int start = t * chunk;
    int end   = min(start + chunk, n);
    int s = 0;
    for (int i = start; i < end; i++) s += cnt[i];
    ssum[t] = s;
    __syncthreads();
    for (int off = 1; off < 1024; off <<= 1) {
        int v = (t >= off) ? ssum[t - off] : 0;
        __syncthreads();
        ssum[t] += v;
        __syncthreads();
    }
    int base = (t > 0) ? ssum[t - 1] : 0;
    for (int i = start; i < end; i++) {
        int c = cnt[i];
        ptr[i] = base;
        cnt[i] = base;   // scatter cursor
        base += c;
    }
    if (t == 0) ptr[n] = ssum[1023];
}

// ---------------------------------------------------------------------------
// Region-limited scatter: only edges whose destination falls in the given
// row/col window are stored this pass -> store working set stays L2-resident,
// lines fill fully before eviction (kills the 8x write amplification).
// ---------------------------------------------------------------------------
__global__ __launch_bounds__(256) void scatter_pass(
    const int* __restrict__ rows, const int* __restrict__ cols,
    const float* __restrict__ vals, int nnz,
    int* __restrict__ curR, int* __restrict__ curC,
    int2* __restrict__ byR, int2* __restrict__ byC,
    int rlo, int rhi, int clo, int chi)
{
    int i = blockIdx.x * 256 + threadIdx.x;
    if (i >= nnz) return;
    int r = rows[i], c = cols[i];
    bool mr = (r >= rlo) & (r < rhi);
    bool mc = (c >= clo) & (c < chi);
    if (mr | mc) {
        int vb = __float_as_int(vals[i]);
        if (mr) { int p = atomicAdd(&curR[r], 1); byR[p] = make_int2(c, vb); }
        if (mc) { int q = atomicAdd(&curC[c], 1); byC[q] = make_int2(r, vb); }
    }
}

// ---------------------------------------------------------------------------
// Initial fp32 -> bf16 copies of E_u_0 / E_i_0.
// ---------------------------------------------------------------------------
__global__ __launch_bounds__(256) void to_bf16_init(
    const float* __restrict__ Eu0, const float* __restrict__ Ei0,
    unsigned short* __restrict__ Eu16, unsigned short* __restrict__ Ei16)
{
    const size_t SU = (size_t)NU * DIMK, SI = (size_t)NI * DIMK;
    size_t i = ((size_t)blockIdx.x * 256 + threadIdx.x) * 4;
    if (i < SU) {
        float4 v = *(const float4*)(Eu0 + i);
        Eu16[i+0]=f2bf(v.x); Eu16[i+1]=f2bf(v.y); Eu16[i+2]=f2bf(v.z); Eu16[i+3]=f2bf(v.w);
    } else if (i < SU + SI) {
        size_t j = i - SU;
        float4 v = *(const float4*)(Ei0 + j);
        Ei16[j+0]=f2bf(v.x); Ei16[j+1]=f2bf(v.y); Ei16[j+2]=f2bf(v.z); Ei16[j+3]=f2bf(v.w);
    }
}

// ---------------------------------------------------------------------------
// Gather SpMM, all 4 products in one dispatch. One wave per output row,
// lane k owns element k; pos+neg lists both handled by the same wave.
// X is bf16 (128B per edge-row read), accumulation fp32.
// ---------------------------------------------------------------------------
__device__ inline float row_gather(
    const int* __restrict__ ptr, const int2* __restrict__ edges,
    const unsigned short* __restrict__ X, int r, int lane)
{
    int beg = ptr[r], end = ptr[r + 1];
    float acc = 0.f;
    for (int e0 = beg; e0 < end; e0 += 64) {
        int2 ed = make_int2(0, 0);
        if (e0 + lane < end) ed = edges[e0 + lane];
        int nb = min(64, end - e0);
#pragma unroll 4
        for (int j = 0; j < nb; j++) {
            int   col = __shfl(ed.x, j, 64);
            float v   = __int_as_float(__shfl(ed.y, j, 64));
            acc = fmaf(v, bf2f(X[(size_t)col * DIMK + lane]), acc);
        }
    }
    return acc;
}

__global__ __launch_bounds__(256) void spmm_fused(
    const int* __restrict__ ptr_pr, const int2* __restrict__ byR_p,
    const int* __restrict__ ptr_nr, const int2* __restrict__ byR_n,
    const int* __restrict__ ptr_pc, const int2* __restrict__ byC_p,
    const int* __restrict__ ptr_nc, const int2* __restrict__ byC_n,
    const unsigned short* __restrict__ Eu16, const unsigned short* __restrict__ Ei16,
    float* __restrict__ Zup, float* __restrict__ Zun,
    float* __restrict__ Zip, float* __restrict__ Zin)
{
    int wid  = (blockIdx.x * 256 + threadIdx.x) >> 6;
    int lane = threadIdx.x & 63;
    const int* pP; const int2* eP; const int* pN; const int2* eN;
    const unsigned short* X; float* Zp; float* Zn; int r;
    if (wid < NU) {
        r = wid; pP = ptr_pr; eP = byR_p; pN = ptr_nr; eN = byR_n;
        X = Ei16; Zp = Zup; Zn = Zun;
    } else if (wid < NU + NI) {
        r = wid - NU; pP = ptr_pc; eP = byC_p; pN = ptr_nc; eN = byC_n;
        X = Eu16; Zp = Zip; Zn = Zin;
    } else return;
    float ap = row_gather(pP, eP, X, r, lane);
    float an = row_gather(pN, eN, X, r, lane);
    Zp[(size_t)r * DIMK + lane] = ap;
    Zn[(size_t)r * DIMK + lane] = an;
}

// ---------------------------------------------------------------------------
// Fused 5-term linear + leaky-relu for BOTH sides in one dispatch.
// In-place into Zp; also writes the bf16 copy for the next layer's spmm.
// ---------------------------------------------------------------------------
__global__ __launch_bounds__(256) void linear_fuse2(
    const float* __restrict__ Xu, float* __restrict__ Zup, const float* __restrict__ Zun,
    const float* __restrict__ Wu, const float* __restrict__ bu,
    const float* __restrict__ Xi, float* __restrict__ Zip, const float* __restrict__ Zin,
    const float* __restrict__ Wi, const float* __restrict__ bi,
    unsigned short* __restrict__ Eu16, unsigned short* __restrict__ Ei16)
{
    __shared__ float Ws[5 * 64 * 64];  // [t][k][j], 80 KiB
    int tid = threadIdx.x;

    const float* Xe; float* Zp; const float* Zn; const float* W; const float* b;
    unsigned short* E16; int N; int blk;
    if (blockIdx.x < NBU) {
        Xe = Xu; Zp = Zup; Zn = Zun; W = Wu; b = bu; E16 = Eu16; N = NU; blk = blockIdx.x;
    } else {
        Xe = Xi; Zp = Zip; Zn = Zin; W = Wi; b = bi; E16 = Ei16; N = NI; blk = blockIdx.x - NBU;
    }

    for (int g = tid; g < 5120; g += 256) {
        int j0 = g & 63;
        int kq = (g >> 6) & 15;
        int t  = g >> 10;
        float4 w = *(const float4*)(W + (size_t)t * 4096 + (size_t)j0 * 64 + kq * 4);
        int base = t * 4096 + kq * 4 * 64 + j0;
        Ws[base +   0] = w.x;
        Ws[base +  64] = w.y;
        Ws[base + 128] = w.z;
        Ws[base + 192] = w.w;
    }

    int j  = tid & 63;
    int rq = tid >> 6;
    float bsum = b[j] + b[64 + j] + b[128 + j] + b[192 + j] + b[256 + j];
    __syncthreads();

    int r_base = blk * 16 + rq * 4;
    int rr[4];
#pragma unroll
    for (int i = 0; i < 4; i++) {
        int r = r_base + i;
        rr[i] = (r < N) ? r : (N - 1);
    }

    float acc[4] = {bsum, bsum, bsum, bsum};

    for (int k4 = 0; k4 < 64; k4 += 4) {
        float4 e4[4], p4[4], n4[4];
#pragma unroll
        for (int i = 0; i < 4; i++) {
            e4[i] = *(const float4*)(Xe + (size_t)rr[i] * 64 + k4);
            p4[i] = *(const float4*)(Zp + (size_t)rr[i] * 64 + k4);
            n4[i] = *(const float4*)(Zn + (size_t)rr[i] * 64 + k4);
        }
#pragma unroll
        for (int q = 0; q < 4; q++) {
            int k = k4 + q;
            float w0 = Ws[            k * 64 + j];
            float w1 = Ws[ 4096 +     k * 64 + j];
            float w2 = Ws[ 8192 +     k * 64 + j];
            float w3 = Ws[12288 +     k * 64 + j];
            float w4 = Ws[16384 +     k * 64 + j];
#pragma unroll
            for (int i = 0; i < 4; i++) {
                float e  = ((const float*)&e4[i])[q];
                float zp = ((const float*)&p4[i])[q];
                float zn = ((const float*)&n4[i])[q];
                acc[i] = fmaf(e,      w0, acc[i]);
                acc[i] = fmaf(zp,     w1, acc[i]);
                acc[i] = fmaf(zp * e, w2, acc[i]);
                acc[i] = fmaf(zn,     w3, acc[i]);
                acc[i] = fmaf(zn * e, w4, acc[i]);
            }
        }
    }

    __syncthreads();  // all reads of this block's Zp rows done before overwrite
#pragma unroll
    for (int i = 0; i < 4; i++) {
        int r = r_base + i;
        if (r < N) {
            float m = acc[i];
            float o = (m > 0.f) ? m : 0.2f * m;
            Zp[(size_t)r * 64 + j] = o;
            E16[(size_t)r * 64 + j] = f2bf(o);
        }
    }
}

// ---------------------------------------------------------------------------
// Final gather: normalize u rows, logits, partial loss per block.
// ---------------------------------------------------------------------------
__global__ __launch_bounds__(256) void finalize_kernel(
    const float* __restrict__ Eu, const float* __restrict__ Ei,
    const int* __restrict__ uids, const int* __restrict__ iids,
    const float* __restrict__ labels,
    float* __restrict__ out, float* __restrict__ partials)
{
    int bidx = blockIdx.x * 256 + threadIdx.x;
    float part = 0.f;
    if (bidx < BQ) {
        const float4* u4 = (const float4*)(Eu + (size_t)uids[bidx] * 64);
        const float4* i4 = (const float4*)(Ei + (size_t)iids[bidx] * 64);
        float nrm = 0.f, dot = 0.f, regi = 0.f;
#pragma unroll
        for (int q = 0; q < 16; q++) {
            float4 u = u4[q], w = i4[q];
            nrm  += u.x * u.x + u.y * u.y + u.z * u.z + u.w * u.w;
            dot  += u.x * w.x + u.y * w.y + u.z * w.z + u.w * w.w;
            regi += w.x * w.x + w.y * w.y + w.z * w.z + w.w * w.w;
        }
        float inv   = 1.f / fmaxf(sqrtf(nrm), 1e-12f);
        float logit = dot * inv;
        out[1 + bidx] = logit;
        float regu = nrm * inv * inv;
        float y  = labels[bidx];
        float sp = fmaxf(logit, 0.f) + log1pf(expf(-fabsf(logit)));
        part = (sp - logit * y) * (1.f / (float)BQ) + 1e-6f * (regu + regi);
    }
    __shared__ float red[256];
    red[threadIdx.x] = part;
    __syncthreads();
    for (int s = 128; s > 0; s >>= 1) {
        if (threadIdx.x < s) red[threadIdx.x] += red[threadIdx.x + s];
        __syncthreads();
    }
    if (threadIdx.x == 0) partials[blockIdx.x] = red[0];
}

__global__ void reduce_loss(const float* __restrict__ partials, float* __restrict__ out)
{
    if (threadIdx.x == 0) {
        float s = 0.f;
        for (int i = 0; i < 32; i++) s += partials[i];
        out[0] = s;
    }
}

// ---------------------------------------------------------------------------
extern "C" void kernel_launch(void* const* d_in, const int* in_sizes, int n_in,
                              void* d_out, int out_size, void* d_ws, size_t ws_size,
                              hipStream_t stream)
{
    const int*   pos_rows = (const int*)d_in[0];
    const int*   pos_cols = (const int*)d_in[1];
    const float* pos_vals = (const float*)d_in[2];
    const int*   neg_rows = (const int*)d_in[3];
    const int*   neg_cols = (const int*)d_in[4];
    const float* neg_vals = (const float*)d_in[5];
    const int*   uids     = (const int*)d_in[6];
    const int*   iids     = (const int*)d_in[7];
    const float* labels   = (const float*)d_in[8];
    const float* E_u_0    = (const float*)d_in[9];
    const float* E_i_0    = (const float*)d_in[10];
    const float* W_u      = (const float*)d_in[11];
    const float* b_u      = (const float*)d_in[12];
    const float* W_i      = (const float*)d_in[13];
    const float* b_i      = (const float*)d_in[14];

    char* base = (char*)d_ws;
    size_t off = 0;
    auto alloc = [&](size_t bytes) { char* p = base + off; off += (bytes + 255) & ~(size_t)255; return p; };

    const size_t SU = (size_t)NU * DIMK;
    const size_t SI = (size_t)NI * DIMK;
    float* Ub[3]; float* Ib[3];
    for (int i = 0; i < 3; i++) Ub[i] = (float*)alloc(SU * 4);
    for (int i = 0; i < 3; i++) Ib[i] = (float*)alloc(SI * 4);
    int2* byR_p = (int2*)alloc((size_t)NNZP * 8);
    int2* byC_p = (int2*)alloc((size_t)NNZP * 8);
    int2* byR_n = (int2*)alloc((size_t)NNZN * 8);
    int2* byC_n = (int2*)alloc((size_t)NNZN * 8);
    unsigned short* Eu16 = (unsigned short*)alloc(SU * 2);
    unsigned short* Ei16 = (unsigned short*)alloc(SI * 2);
    int* ptr_pr = (int*)alloc((NU + 1) * 4);
    int* ptr_pc = (int*)alloc((NI + 1) * 4);
    int* ptr_nr = (int*)alloc((NU + 1) * 4);
    int* ptr_nc = (int*)alloc((NI + 1) * 4);
    int* cnt_all = (int*)alloc((size_t)(2 * NU + 2 * NI) * 4);  // contiguous
    int* cnt_pr = cnt_all;
    int* cnt_pc = cnt_all + NU;
    int* cnt_nr = cnt_all + NU + NI;
    int* cnt_nc = cnt_all + 2 * NU + NI;
    float* partials = (float*)alloc(32 * 4);

    // ---- CSR/CSC build ----
    hipMemsetAsync(cnt_all, 0, (size_t)(2 * NU + 2 * NI) * 4, stream);
    hist_all<<<(NNZP + NNZN + 255) / 256, 256, 0, stream>>>(
        pos_rows, pos_cols, neg_rows, neg_cols, cnt_pr, cnt_pc, cnt_nr, cnt_nc);
    exscan4<<<4, 1024, 0, stream>>>(cnt_pr, ptr_pr, NU, cnt_pc, ptr_pc, NI,
                                    cnt_nr, ptr_nr, NU, cnt_nc, ptr_nc, NI);
    for (int k = 0; k < NREG; k++) {
        int rlo = (int)((long long)NU * k / NREG), rhi = (int)((long long)NU * (k + 1) / NREG);
        int clo = (int)((long long)NI * k / NREG), chi = (int)((long long)NI * (k + 1) / NREG);
        scatter_pass<<<(NNZP + 255) / 256, 256, 0, stream>>>(
            pos_rows, pos_cols, pos_vals, NNZP, cnt_pr, cnt_pc, byR_p, byC_p, rlo, rhi, clo, chi);
        scatter_pass<<<(NNZN + 255) / 256, 256, 0, stream>>>(
            neg_rows, neg_cols, neg_vals, NNZN, cnt_nr, cnt_nc, byR_n, byC_n, rlo, rhi, clo, chi);
    }

    to_bf16_init<<<(int)((SU + SI) / 4 + 255) / 256, 256, 0, stream>>>(E_u_0, E_i_0, Eu16, Ei16);

    // ---- 3 GCN layers ----
    const float* Eu_cur = E_u_0;
    const float* Ei_cur = E_i_0;
    for (int l = 0; l < 3; l++) {
        float* Zup = Ub[l];
        float* Zun = Ub[(l + 1) % 3];
        float* Zip = Ib[l];
        float* Zin = Ib[(l + 1) % 3];

        spmm_fused<<<(NU + NI + 3) / 4, 256, 0, stream>>>(
            ptr_pr, byR_p, ptr_nr, byR_n, ptr_pc, byC_p, ptr_nc, byC_n,
            Eu16, Ei16, Zup, Zun, Zip, Zin);

        linear_fuse2<<<NBU + NBI, 256, 0, stream>>>(
            Eu_cur, Zup, Zun, W_u + (size_t)l * 5 * 64 * 64, b_u + (size_t)l * 5 * 64,
            Ei_cur, Zip, Zin, W_i + (size_t)l * 5 * 64 * 64, b_i + (size_t)l * 5 * 64,
            Eu16, Ei16);

        Eu_cur = Zup;
        Ei_cur = Zip;
    }

    finalize_kernel<<<BQ / 256, 256, 0, stream>>>(
        Eu_cur, Ei_cur, uids, iids, labels, (float*)d_out, partials);
    reduce_loss<<<1, 64, 0, stream>>>(partials, (float*)d_out);
}

// Round 4
// 2560.614 us; speedup vs baseline: 6.3163x; 1.0484x over previous
//
#include <hip/hip_runtime.h>
#include <cstdint>
#include <cstddef>

#define NU 100000
#define NI 50000
#define DIMK 64
#define NNZP 2000000
#define NNZN 1000000
#define BQ 8192
#define NREG 4          // scatter destination regions
#define NBU2 3125       // NU/32 blocks for u-linear (exact)
#define NBI2 1563       // ceil(NI/32) blocks for i-linear

typedef float v2f __attribute__((ext_vector_type(2)));

__device__ inline unsigned short f2bf(float f) {   // RNE fp32 -> bf16
    unsigned u = __float_as_uint(f);
    unsigned r = (u + 0x7fffu + ((u >> 16) & 1u)) >> 16;
    return (unsigned short)r;
}
__device__ inline float bf2f(unsigned short h) {
    return __uint_as_float(((unsigned)h) << 16);
}

// ---------------------------------------------------------------------------
// Fused histogram over pos+neg COO, both key directions.
// ---------------------------------------------------------------------------
__global__ __launch_bounds__(256) void hist_all(
    const int* __restrict__ pr, const int* __restrict__ pc,
    const int* __restrict__ nr, const int* __restrict__ nc,
    int* __restrict__ cnt_pr, int* __restrict__ cnt_pc,
    int* __restrict__ cnt_nr, int* __restrict__ cnt_nc)
{
    int i = blockIdx.x * 256 + threadIdx.x;
    if (i < NNZP) {
        atomicAdd(&cnt_pr[pr[i]], 1);
        atomicAdd(&cnt_pc[pc[i]], 1);
    } else if (i < NNZP + NNZN) {
        int j = i - NNZP;
        atomicAdd(&cnt_nr[nr[j]], 1);
        atomicAdd(&cnt_nc[nc[j]], 1);
    }
}

// ---------------------------------------------------------------------------
// Exclusive scan of 4 count arrays (one block each). cnt[] becomes cursor.
// ---------------------------------------------------------------------------
__global__ __launch_bounds__(1024) void exscan4(
    int* c0, int* p0, int n0, int* c1, int* p1, int n1,
    int* c2, int* p2, int n2, int* c3, int* p3, int n3)
{
    int* cnt; int* ptr; int n;
    switch (blockIdx.x) {
        case 0:  cnt = c0; ptr = p0; n = n0; break;
        case 1:  cnt = c1; ptr = p1; n = n1; break;
        case 2:  cnt = c2; ptr = p2; n = n2; break;
        default: cnt = c3; ptr = p3; n = n3; break;
    }
    __shared__ int ssum[1024];
    int t = threadIdx.x;
    int chunk = (n + 1023) >> 10;
    int start = t * chunk;
    int end   = min(start + chunk, n);
    int s = 0;
    for (int i = start; i < end; i++) s += cnt[i];
    ssum[t] = s;
    __syncthreads();
    for (int off = 1; off < 1024; off <<= 1) {
        int v = (t >= off) ? ssum[t - off] : 0;
        __syncthreads();
        ssum[t] += v;
        __syncthreads();
    }
    int base = (t > 0) ? ssum[t - 1] : 0;
    for (int i = start; i < end; i++) {
        int c = cnt[i];
        ptr[i] = base;
        cnt[i] = base;   // scatter cursor
        base += c;
    }
    if (t == 0) ptr[n] = ssum[1023];
}

// ---------------------------------------------------------------------------
// Region-limited scatter (store working set stays L2-resident).
// ---------------------------------------------------------------------------
__global__ __launch_bounds__(256) void scatter_pass(
    const int* __restrict__ rows, const int* __restrict__ cols,
    const float* __restrict__ vals, int nnz,
    int* __restrict__ curR, int* __restrict__ curC,
    int2* __restrict__ byR, int2* __restrict__ byC,
    int rlo, int rhi, int clo, int chi)
{
    int i = blockIdx.x * 256 + threadIdx.x;
    if (i >= nnz) return;
    int r = rows[i], c = cols[i];
    bool mr = (r >= rlo) & (r < rhi);
    bool mc = (c >= clo) & (c < chi);
    if (mr | mc) {
        int vb = __float_as_int(vals[i]);
        if (mr) { int p = atomicAdd(&curR[r], 1); byR[p] = make_int2(c, vb); }
        if (mc) { int q = atomicAdd(&curC[c], 1); byC[q] = make_int2(r, vb); }
    }
}

// ---------------------------------------------------------------------------
// Initial fp32 -> bf16 copies of E_u_0 / E_i_0.
// ---------------------------------------------------------------------------
__global__ __launch_bounds__(256) void to_bf16_init(
    const float* __restrict__ Eu0, const float* __restrict__ Ei0,
    unsigned short* __restrict__ Eu16, unsigned short* __restrict__ Ei16)
{
    const size_t SU = (size_t)NU * DIMK, SI = (size_t)NI * DIMK;
    size_t i = ((size_t)blockIdx.x * 256 + threadIdx.x) * 4;
    if (i < SU) {
        float4 v = *(const float4*)(Eu0 + i);
        Eu16[i+0]=f2bf(v.x); Eu16[i+1]=f2bf(v.y); Eu16[i+2]=f2bf(v.z); Eu16[i+3]=f2bf(v.w);
    } else if (i < SU + SI) {
        size_t j = i - SU;
        float4 v = *(const float4*)(Ei0 + j);
        Ei16[j+0]=f2bf(v.x); Ei16[j+1]=f2bf(v.y); Ei16[j+2]=f2bf(v.z); Ei16[j+3]=f2bf(v.w);
    }
}

// ---------------------------------------------------------------------------
// Gather SpMM, all 4 products in one dispatch. One wave per output row.
// ---------------------------------------------------------------------------
__device__ inline float row_gather(
    const int* __restrict__ ptr, const int2* __restrict__ edges,
    const unsigned short* __restrict__ X, int r, int lane)
{
    int beg = ptr[r], end = ptr[r + 1];
    float acc = 0.f;
    for (int e0 = beg; e0 < end; e0 += 64) {
        int2 ed = make_int2(0, 0);
        if (e0 + lane < end) ed = edges[e0 + lane];
        int nb = min(64, end - e0);
#pragma unroll 4
        for (int j = 0; j < nb; j++) {
            int   col = __shfl(ed.x, j, 64);
            float v   = __int_as_float(__shfl(ed.y, j, 64));
            acc = fmaf(v, bf2f(X[(size_t)col * DIMK + lane]), acc);
        }
    }
    return acc;
}

__global__ __launch_bounds__(256) void spmm_fused(
    const int* __restrict__ ptr_pr, const int2* __restrict__ byR_p,
    const int* __restrict__ ptr_nr, const int2* __restrict__ byR_n,
    const int* __restrict__ ptr_pc, const int2* __restrict__ byC_p,
    const int* __restrict__ ptr_nc, const int2* __restrict__ byC_n,
    const unsigned short* __restrict__ Eu16, const unsigned short* __restrict__ Ei16,
    float* __restrict__ Zup, float* __restrict__ Zun,
    float* __restrict__ Zip, float* __restrict__ Zin)
{
    int wid  = (blockIdx.x * 256 + threadIdx.x) >> 6;
    int lane = threadIdx.x & 63;
    const int* pP; const int2* eP; const int* pN; const int2* eN;
    const unsigned short* X; float* Zp; float* Zn; int r;
    if (wid < NU) {
        r = wid; pP = ptr_pr; eP = byR_p; pN = ptr_nr; eN = byR_n;
        X = Ei16; Zp = Zup; Zn = Zun;
    } else if (wid < NU + NI) {
        r = wid - NU; pP = ptr_pc; eP = byC_p; pN = ptr_nc; eN = byC_n;
        X = Eu16; Zp = Zip; Zn = Zin;
    } else return;
    float ap = row_gather(pP, eP, X, r, lane);
    float an = row_gather(pN, eN, X, r, lane);
    Zp[(size_t)r * DIMK + lane] = ap;
    Zn[(size_t)r * DIMK + lane] = an;
}

// ---------------------------------------------------------------------------
// Fused 5-term linear + leaky-relu, both sides in one dispatch.
// Ws layout [t][kq][j][4] -> one ds_read_b128 per term per k4-step.
// 8 rows/wave, k-even/odd packed into float2 -> v_pk_fma_f32.
// ---------------------------------------------------------------------------
__global__ __launch_bounds__(256) void linear_fuse2(
    const float* __restrict__ Xu, float* __restrict__ Zup, const float* __restrict__ Zun,
    const float* __restrict__ Wu, const float* __restrict__ bu,
    const float* __restrict__ Xi, float* __restrict__ Zip, const float* __restrict__ Zin,
    const float* __restrict__ Wi, const float* __restrict__ bi,
    unsigned short* __restrict__ Eu16, unsigned short* __restrict__ Ei16)
{
    __shared__ float4 Ws4[5 * 16 * 64];  // [t][kq][j], float4 over q. 80 KiB
    int tid = threadIdx.x;

    const float* Xe; float* Zp; const float* Zn; const float* W; const float* b;
    unsigned short* E16; int N; int blk;
    if (blockIdx.x < NBU2) {
        Xe = Xu; Zp = Zup; Zn = Zun; W = Wu; b = bu; E16 = Eu16; N = NU; blk = blockIdx.x;
    } else {
        Xe = Xi; Zp = Zip; Zn = Zin; W = Wi; b = bi; E16 = Ei16; N = NI; blk = blockIdx.x - NBU2;
    }

    // stage W[t][j][k] -> Ws4[(t*16+kq)*64 + j] = {W[t][j][4kq..4kq+3]}
    // j fastest over lanes -> conflict-free b128 LDS stores.
    for (int g = tid; g < 5120; g += 256) {
        int j0 = g & 63;
        int kq = (g >> 6) & 15;
        int t  = g >> 10;
        float4 w = *(const float4*)(W + (size_t)t * 4096 + (size_t)j0 * 64 + kq * 4);
        Ws4[(t * 16 + kq) * 64 + j0] = w;
    }

    int j  = tid & 63;
    int wv = tid >> 6;
    float bsum = b[j] + b[64 + j] + b[128 + j] + b[192 + j] + b[256 + j];
    __syncthreads();

    int r0 = blk * 32 + wv * 8;
    int ro[8];
#pragma unroll
    for (int i = 0; i < 8; i++) {
        int r = r0 + i;
        ro[i] = ((r < N) ? r : (N - 1)) * 64;  // clamp loads; stores guarded
    }

    v2f acc[8];
#pragma unroll
    for (int i = 0; i < 8; i++) acc[i] = (v2f){0.f, 0.f};

    for (int kq = 0; kq < 16; kq++) {
        float4 w0 = Ws4[(0 * 16 + kq) * 64 + j];
        float4 w1 = Ws4[(1 * 16 + kq) * 64 + j];
        float4 w2 = Ws4[(2 * 16 + kq) * 64 + j];
        float4 w3 = Ws4[(3 * 16 + kq) * 64 + j];
        float4 w4 = Ws4[(4 * 16 + kq) * 64 + j];
        v2f w0l = {w0.x, w0.y}, w0h = {w0.z, w0.w};
        v2f w1l = {w1.x, w1.y}, w1h = {w1.z, w1.w};
        v2f w2l = {w2.x, w2.y}, w2h = {w2.z, w2.w};
        v2f w3l = {w3.x, w3.y}, w3h = {w3.z, w3.w};
        v2f w4l = {w4.x, w4.y}, w4h = {w4.z, w4.w};
        int ko = kq * 4;
#pragma unroll
        for (int i = 0; i < 8; i++) {
            float4 e4 = *(const float4*)(Xe + ro[i] + ko);
            float4 p4 = *(const float4*)(Zp + ro[i] + ko);
            float4 n4 = *(const float4*)(Zn + ro[i] + ko);
            v2f el = {e4.x, e4.y}, eh = {e4.z, e4.w};
            v2f pl = {p4.x, p4.y}, ph = {p4.z, p4.w};
            v2f nl = {n4.x, n4.y}, nh = {n4.z, n4.w};
            v2f a = acc[i];
            a = __builtin_elementwise_fma(el,      w0l, a);
            a = __builtin_elementwise_fma(eh,      w0h, a);
            a = __builtin_elementwise_fma(pl,      w1l, a);
            a = __builtin_elementwise_fma(ph,      w1h, a);
            a = __builtin_elementwise_fma(pl * el, w2l, a);
            a = __builtin_elementwise_fma(ph * eh, w2h, a);
            a = __builtin_elementwise_fma(nl,      w3l, a);
            a = __builtin_elementwise_fma(nh,      w3h, a);
            a = __builtin_elementwise_fma(nl * el, w4l, a);
            a = __builtin_elementwise_fma(nh * eh, w4h, a);
            acc[i] = a;
        }
    }

    __syncthreads();  // all reads of this block's Zp rows done before overwrite
#pragma unroll
    for (int i = 0; i < 8; i++) {
        int r = r0 + i;
        if (r < N) {
            float m = bsum + acc[i].x + acc[i].y;
            float o = (m > 0.f) ? m : 0.2f * m;
            Zp[(size_t)r * 64 + j] = o;
            E16[(size_t)r * 64 + j] = f2bf(o);
        }
    }
}

// ---------------------------------------------------------------------------
// Final gather: normalize u rows, logits, partial loss per block.
// ---------------------------------------------------------------------------
__global__ __launch_bounds__(256) void finalize_kernel(
    const float* __restrict__ Eu, const float* __restrict__ Ei,
    const int* __restrict__ uids, const int* __restrict__ iids,
    const float* __restrict__ labels,
    float* __restrict__ out, float* __restrict__ partials)
{
    int bidx = blockIdx.x * 256 + threadIdx.x;
    float part = 0.f;
    if (bidx < BQ) {
        const float4* u4 = (const float4*)(Eu + (size_t)uids[bidx] * 64);
        const float4* i4 = (const float4*)(Ei + (size_t)iids[bidx] * 64);
        float nrm = 0.f, dot = 0.f, regi = 0.f;
#pragma unroll
        for (int q = 0; q < 16; q++) {
            float4 u = u4[q], w = i4[q];
            nrm  += u.x * u.x + u.y * u.y + u.z * u.z + u.w * u.w;
            dot  += u.x * w.x + u.y * w.y + u.z * w.z + u.w * w.w;
            regi += w.x * w.x + w.y * w.y + w.z * w.z + w.w * w.w;
        }
        float inv   = 1.f / fmaxf(sqrtf(nrm), 1e-12f);
        float logit = dot * inv;
        out[1 + bidx] = logit;
        float regu = nrm * inv * inv;
        float y  = labels[bidx];
        float sp = fmaxf(logit, 0.f) + log1pf(expf(-fabsf(logit)));
        part = (sp - logit * y) * (1.f / (float)BQ) + 1e-6f * (regu + regi);
    }
    __shared__ float red[256];
    red[threadIdx.x] = part;
    __syncthreads();
    for (int s = 128; s > 0; s >>= 1) {
        if (threadIdx.x < s) red[threadIdx.x] += red[threadIdx.x + s];
        __syncthreads();
    }
    if (threadIdx.x == 0) partials[blockIdx.x] = red[0];
}

__global__ void reduce_loss(const float* __restrict__ partials, float* __restrict__ out)
{
    if (threadIdx.x == 0) {
        float s = 0.f;
        for (int i = 0; i < 32; i++) s += partials[i];
        out[0] = s;
    }
}

// ---------------------------------------------------------------------------
extern "C" void kernel_launch(void* const* d_in, const int* in_sizes, int n_in,
                              void* d_out, int out_size, void* d_ws, size_t ws_size,
                              hipStream_t stream)
{
    const int*   pos_rows = (const int*)d_in[0];
    const int*   pos_cols = (const int*)d_in[1];
    const float* pos_vals = (const float*)d_in[2];
    const int*   neg_rows = (const int*)d_in[3];
    const int*   neg_cols = (const int*)d_in[4];
    const float* neg_vals = (const float*)d_in[5];
    const int*   uids     = (const int*)d_in[6];
    const int*   iids     = (const int*)d_in[7];
    const float* labels   = (const float*)d_in[8];
    const float* E_u_0    = (const float*)d_in[9];
    const float* E_i_0    = (const float*)d_in[10];
    const float* W_u      = (const float*)d_in[11];
    const float* b_u      = (const float*)d_in[12];
    const float* W_i      = (const float*)d_in[13];
    const float* b_i      = (const float*)d_in[14];

    char* base = (char*)d_ws;
    size_t off = 0;
    auto alloc = [&](size_t bytes) { char* p = base + off; off += (bytes + 255) & ~(size_t)255; return p; };

    const size_t SU = (size_t)NU * DIMK;
    const size_t SI = (size_t)NI * DIMK;
    float* Ub[3]; float* Ib[3];
    for (int i = 0; i < 3; i++) Ub[i] = (float*)alloc(SU * 4);
    for (int i = 0; i < 3; i++) Ib[i] = (float*)alloc(SI * 4);
    int2* byR_p = (int2*)alloc((size_t)NNZP * 8);
    int2* byC_p = (int2*)alloc((size_t)NNZP * 8);
    int2* byR_n = (int2*)alloc((size_t)NNZN * 8);
    int2* byC_n = (int2*)alloc((size_t)NNZN * 8);
    unsigned short* Eu16 = (unsigned short*)alloc(SU * 2);
    unsigned short* Ei16 = (unsigned short*)alloc(SI * 2);
    int* ptr_pr = (int*)alloc((NU + 1) * 4);
    int* ptr_pc = (int*)alloc((NI + 1) * 4);
    int* ptr_nr = (int*)alloc((NU + 1) * 4);
    int* ptr_nc = (int*)alloc((NI + 1) * 4);
    int* cnt_all = (int*)alloc((size_t)(2 * NU + 2 * NI) * 4);  // contiguous
    int* cnt_pr = cnt_all;
    int* cnt_pc = cnt_all + NU;
    int* cnt_nr = cnt_all + NU + NI;
    int* cnt_nc = cnt_all + 2 * NU + NI;
    float* partials = (float*)alloc(32 * 4);

    // ---- CSR/CSC build ----
    hipMemsetAsync(cnt_all, 0, (size_t)(2 * NU + 2 * NI) * 4, stream);
    hist_all<<<(NNZP + NNZN + 255) / 256, 256, 0, stream>>>(
        pos_rows, pos_cols, neg_rows, neg_cols, cnt_pr, cnt_pc, cnt_nr, cnt_nc);
    exscan4<<<4, 1024, 0, stream>>>(cnt_pr, ptr_pr, NU, cnt_pc, ptr_pc, NI,
                                    cnt_nr, ptr_nr, NU, cnt_nc, ptr_nc, NI);
    for (int k = 0; k < NREG; k++) {
        int rlo = (int)((long long)NU * k / NREG), rhi = (int)((long long)NU * (k + 1) / NREG);
        int clo = (int)((long long)NI * k / NREG), chi = (int)((long long)NI * (k + 1) / NREG);
        scatter_pass<<<(NNZP + 255) / 256, 256, 0, stream>>>(
            pos_rows, pos_cols, pos_vals, NNZP, cnt_pr, cnt_pc, byR_p, byC_p, rlo, rhi, clo, chi);
        scatter_pass<<<(NNZN + 255) / 256, 256, 0, stream>>>(
            neg_rows, neg_cols, neg_vals, NNZN, cnt_nr, cnt_nc, byR_n, byC_n, rlo, rhi, clo, chi);
    }

    to_bf16_init<<<(int)((SU + SI) / 4 + 255) / 256, 256, 0, stream>>>(E_u_0, E_i_0, Eu16, Ei16);

    // ---- 3 GCN layers ----
    const float* Eu_cur = E_u_0;
    const float* Ei_cur = E_i_0;
    for (int l = 0; l < 3; l++) {
        float* Zup = Ub[l];
        float* Zun = Ub[(l + 1) % 3];
        float* Zip = Ib[l];
        float* Zin = Ib[(l + 1) % 3];

        spmm_fused<<<(NU + NI + 3) / 4, 256, 0, stream>>>(
            ptr_pr, byR_p, ptr_nr, byR_n, ptr_pc, byC_p, ptr_nc, byC_n,
            Eu16, Ei16, Zup, Zun, Zip, Zin);

        linear_fuse2<<<NBU2 + NBI2, 256, 0, stream>>>(
            Eu_cur, Zup, Zun, W_u + (size_t)l * 5 * 64 * 64, b_u + (size_t)l * 5 * 64,
            Ei_cur, Zip, Zin, W_i + (size_t)l * 5 * 64 * 64, b_i + (size_t)l * 5 * 64,
            Eu16, Ei16);

        Eu_cur = Zup;
        Ei_cur = Zip;
    }

    finalize_kernel<<<BQ / 256, 256, 0, stream>>>(
        Eu_cur, Ei_cur, uids, iids, labels, (float*)d_out, partials);
    reduce_loss<<<1, 64, 0, stream>>>(partials, (float*)d_out);
}

// Round 5
// 2058.556 us; speedup vs baseline: 7.8568x; 1.2439x over previous
//
#include <hip/hip_runtime.h>
#include <cstdint>
#include <cstddef>

#define NU 100000
#define NI 50000
#define DIMK 64
#define NNZP 2000000
#define NNZN 1000000
#define BQ 8192
#define NBU2 3125       // NU/32 blocks for u-linear (exact)
#define NBI2 1563       // ceil(NI/32) blocks for i-linear

typedef float v2f __attribute__((ext_vector_type(2)));

__device__ inline unsigned short f2bf(float f) {   // RNE fp32 -> bf16
    unsigned u = __float_as_uint(f);
    unsigned r = (u + 0x7fffu + ((u >> 16) & 1u)) >> 16;
    return (unsigned short)r;
}
__device__ inline float bf2f(unsigned short h) {
    return __uint_as_float(((unsigned)h) << 16);
}

// ---------------------------------------------------------------------------
// Fused histogram over pos+neg COO, both key directions.
// ---------------------------------------------------------------------------
__global__ __launch_bounds__(256) void hist_all(
    const int* __restrict__ pr, const int* __restrict__ pc,
    const int* __restrict__ nr, const int* __restrict__ nc,
    int* __restrict__ cnt_pr, int* __restrict__ cnt_pc,
    int* __restrict__ cnt_nr, int* __restrict__ cnt_nc)
{
    int i = blockIdx.x * 256 + threadIdx.x;
    if (i < NNZP) {
        atomicAdd(&cnt_pr[pr[i]], 1);
        atomicAdd(&cnt_pc[pc[i]], 1);
    } else if (i < NNZP + NNZN) {
        int j = i - NNZP;
        atomicAdd(&cnt_nr[nr[j]], 1);
        atomicAdd(&cnt_nc[nc[j]], 1);
    }
}

// ---------------------------------------------------------------------------
// Exclusive scan of 4 count arrays (one block each). cnt[] becomes cursor.
// ---------------------------------------------------------------------------
__global__ __launch_bounds__(1024) void exscan4(
    int* c0, int* p0, int n0, int* c1, int* p1, int n1,
    int* c2, int* p2, int n2, int* c3, int* p3, int n3)
{
    int* cnt; int* ptr; int n;
    switch (blockIdx.x) {
        case 0:  cnt = c0; ptr = p0; n = n0; break;
        case 1:  cnt = c1; ptr = p1; n = n1; break;
        case 2:  cnt = c2; ptr = p2; n = n2; break;
        default: cnt = c3; ptr = p3; n = n3; break;
    }
    __shared__ int ssum[1024];
    int t = threadIdx.x;
    int chunk = (n + 1023) >> 10;
    int start = t * chunk;
    int end   = min(start + chunk, n);
    int s = 0;
    for (int i = start; i < end; i++) s += cnt[i];
    ssum[t] = s;
    __syncthreads();
    for (int off = 1; off < 1024; off <<= 1) {
        int v = (t >= off) ? ssum[t - off] : 0;
        __syncthreads();
        ssum[t] += v;
        __syncthreads();
    }
    int base = (t > 0) ? ssum[t - 1] : 0;
    for (int i = start; i < end; i++) {
        int c = cnt[i];
        ptr[i] = base;
        cnt[i] = base;   // scatter cursor
        base += c;
    }
    if (t == 0) ptr[n] = ssum[1023];
}

// ---------------------------------------------------------------------------
// Scatter into both sorted edge lists (single pass; write amplification is
// XCD line ping-pong and is not fixable by region splitting).
// ---------------------------------------------------------------------------
__global__ __launch_bounds__(256) void scatter2(
    const int* __restrict__ rows, const int* __restrict__ cols,
    const float* __restrict__ vals, int nnz,
    int* __restrict__ curR, int* __restrict__ curC,
    int2* __restrict__ byR, int2* __restrict__ byC)
{
    int i = blockIdx.x * 256 + threadIdx.x;
    if (i >= nnz) return;
    int r = rows[i], c = cols[i];
    int vb = __float_as_int(vals[i]);
    int p = atomicAdd(&curR[r], 1);
    byR[p] = make_int2(c, vb);
    int q = atomicAdd(&curC[c], 1);
    byC[q] = make_int2(r, vb);
}

// ---------------------------------------------------------------------------
// Initial fp32 -> bf16 copies of E_u_0 / E_i_0.
// ---------------------------------------------------------------------------
__global__ __launch_bounds__(256) void to_bf16_init(
    const float* __restrict__ Eu0, const float* __restrict__ Ei0,
    unsigned short* __restrict__ Eu16, unsigned short* __restrict__ Ei16)
{
    const size_t SU = (size_t)NU * DIMK, SI = (size_t)NI * DIMK;
    size_t i = ((size_t)blockIdx.x * 256 + threadIdx.x) * 4;
    if (i < SU) {
        float4 v = *(const float4*)(Eu0 + i);
        Eu16[i+0]=f2bf(v.x); Eu16[i+1]=f2bf(v.y); Eu16[i+2]=f2bf(v.z); Eu16[i+3]=f2bf(v.w);
    } else if (i < SU + SI) {
        size_t j = i - SU;
        float4 v = *(const float4*)(Ei0 + j);
        Ei16[j+0]=f2bf(v.x); Ei16[j+1]=f2bf(v.y); Ei16[j+2]=f2bf(v.z); Ei16[j+3]=f2bf(v.w);
    }
}

// ---------------------------------------------------------------------------
// Gather SpMM row accumulate. Lane k owns dim k. Edge (col,val) broadcast via
// v_readlane (SALU, no LDS pipe); 16 gather loads in flight per block.
// Inactive edge slots hold (0,0): col=0 is an in-bounds dummy row, val=0.
// ---------------------------------------------------------------------------
__device__ inline float row_gather(
    const int* __restrict__ ptr, const int2* __restrict__ edges,
    const unsigned short* __restrict__ X, int r, int lane)
{
    int beg = ptr[r], end = ptr[r + 1];
    float acc = 0.f;
    for (int e0 = beg; e0 < end; e0 += 64) {
        int2 ed = make_int2(0, 0);
        if (e0 + lane < end) ed = edges[e0 + lane];
        int nb = min(64, end - e0);
        for (int j = 0; j < nb; j += 16) {
            float x[16];
#pragma unroll
            for (int q = 0; q < 16; q++) {
                int col = __builtin_amdgcn_readlane(ed.x, j + q);
                x[q] = bf2f(X[(size_t)(unsigned)col * DIMK + lane]);
            }
#pragma unroll
            for (int q = 0; q < 16; q++) {
                float v = __uint_as_float(__builtin_amdgcn_readlane(ed.y, j + q));
                acc = fmaf(v, x[q], acc);
            }
        }
    }
    return acc;
}

__global__ __launch_bounds__(256) void spmm_fused(
    const int* __restrict__ ptr_pr, const int2* __restrict__ byR_p,
    const int* __restrict__ ptr_nr, const int2* __restrict__ byR_n,
    const int* __restrict__ ptr_pc, const int2* __restrict__ byC_p,
    const int* __restrict__ ptr_nc, const int2* __restrict__ byC_n,
    const unsigned short* __restrict__ Eu16, const unsigned short* __restrict__ Ei16,
    float* __restrict__ Zup, float* __restrict__ Zun,
    float* __restrict__ Zip, float* __restrict__ Zin)
{
    int wid  = (blockIdx.x * 256 + threadIdx.x) >> 6;
    int lane = threadIdx.x & 63;
    const int* pP; const int2* eP; const int* pN; const int2* eN;
    const unsigned short* X; float* Zp; float* Zn; int r;
    if (wid < NU) {
        r = wid; pP = ptr_pr; eP = byR_p; pN = ptr_nr; eN = byR_n;
        X = Ei16; Zp = Zup; Zn = Zun;
    } else if (wid < NU + NI) {
        r = wid - NU; pP = ptr_pc; eP = byC_p; pN = ptr_nc; eN = byC_n;
        X = Eu16; Zp = Zip; Zn = Zin;
    } else return;
    float ap = row_gather(pP, eP, X, r, lane);
    float an = row_gather(pN, eN, X, r, lane);
    Zp[(size_t)r * DIMK + lane] = ap;
    Zn[(size_t)r * DIMK + lane] = an;
}

// ---------------------------------------------------------------------------
// Fused 5-term linear + leaky-relu, both sides in one dispatch.
// Ws layout [t][kq][j][4] -> one ds_read_b128 per term per k4-step.
// 8 rows/wave, k-even/odd packed into float2 -> v_pk_fma_f32.
// ---------------------------------------------------------------------------
__global__ __launch_bounds__(256) void linear_fuse2(
    const float* __restrict__ Xu, float* __restrict__ Zup, const float* __restrict__ Zun,
    const float* __restrict__ Wu, const float* __restrict__ bu,
    const float* __restrict__ Xi, float* __restrict__ Zip, const float* __restrict__ Zin,
    const float* __restrict__ Wi, const float* __restrict__ bi,
    unsigned short* __restrict__ Eu16, unsigned short* __restrict__ Ei16)
{
    __shared__ float4 Ws4[5 * 16 * 64];  // [t][kq][j], float4 over q. 80 KiB
    int tid = threadIdx.x;

    const float* Xe; float* Zp; const float* Zn; const float* W; const float* b;
    unsigned short* E16; int N; int blk;
    if (blockIdx.x < NBU2) {
        Xe = Xu; Zp = Zup; Zn = Zun; W = Wu; b = bu; E16 = Eu16; N = NU; blk = blockIdx.x;
    } else {
        Xe = Xi; Zp = Zip; Zn = Zin; W = Wi; b = bi; E16 = Ei16; N = NI; blk = blockIdx.x - NBU2;
    }

    for (int g = tid; g < 5120; g += 256) {
        int j0 = g & 63;
        int kq = (g >> 6) & 15;
        int t  = g >> 10;
        float4 w = *(const float4*)(W + (size_t)t * 4096 + (size_t)j0 * 64 + kq * 4);
        Ws4[(t * 16 + kq) * 64 + j0] = w;
    }

    int j  = tid & 63;
    int wv = tid >> 6;
    float bsum = b[j] + b[64 + j] + b[128 + j] + b[192 + j] + b[256 + j];
    __syncthreads();

    int r0 = blk * 32 + wv * 8;
    int ro[8];
#pragma unroll
    for (int i = 0; i < 8; i++) {
        int r = r0 + i;
        ro[i] = ((r < N) ? r : (N - 1)) * 64;  // clamp loads; stores guarded
    }

    v2f acc[8];
#pragma unroll
    for (int i = 0; i < 8; i++) acc[i] = (v2f){0.f, 0.f};

    for (int kq = 0; kq < 16; kq++) {
        float4 w0 = Ws4[(0 * 16 + kq) * 64 + j];
        float4 w1 = Ws4[(1 * 16 + kq) * 64 + j];
        float4 w2 = Ws4[(2 * 16 + kq) * 64 + j];
        float4 w3 = Ws4[(3 * 16 + kq) * 64 + j];
        float4 w4 = Ws4[(4 * 16 + kq) * 64 + j];
        v2f w0l = {w0.x, w0.y}, w0h = {w0.z, w0.w};
        v2f w1l = {w1.x, w1.y}, w1h = {w1.z, w1.w};
        v2f w2l = {w2.x, w2.y}, w2h = {w2.z, w2.w};
        v2f w3l = {w3.x, w3.y}, w3h = {w3.z, w3.w};
        v2f w4l = {w4.x, w4.y}, w4h = {w4.z, w4.w};
        int ko = kq * 4;
#pragma unroll
        for (int i = 0; i < 8; i++) {
            float4 e4 = *(const float4*)(Xe + ro[i] + ko);
            float4 p4 = *(const float4*)(Zp + ro[i] + ko);
            float4 n4 = *(const float4*)(Zn + ro[i] + ko);
            v2f el = {e4.x, e4.y}, eh = {e4.z, e4.w};
            v2f pl = {p4.x, p4.y}, ph = {p4.z, p4.w};
            v2f nl = {n4.x, n4.y}, nh = {n4.z, n4.w};
            v2f a = acc[i];
            a = __builtin_elementwise_fma(el,      w0l, a);
            a = __builtin_elementwise_fma(eh,      w0h, a);
            a = __builtin_elementwise_fma(pl,      w1l, a);
            a = __builtin_elementwise_fma(ph,      w1h, a);
            a = __builtin_elementwise_fma(pl * el, w2l, a);
            a = __builtin_elementwise_fma(ph * eh, w2h, a);
            a = __builtin_elementwise_fma(nl,      w3l, a);
            a = __builtin_elementwise_fma(nh,      w3h, a);
            a = __builtin_elementwise_fma(nl * el, w4l, a);
            a = __builtin_elementwise_fma(nh * eh, w4h, a);
            acc[i] = a;
        }
    }

    __syncthreads();  // all reads of this block's Zp rows done before overwrite
#pragma unroll
    for (int i = 0; i < 8; i++) {
        int r = r0 + i;
        if (r < N) {
            float m = bsum + acc[i].x + acc[i].y;
            float o = (m > 0.f) ? m : 0.2f * m;
            Zp[(size_t)r * 64 + j] = o;
            E16[(size_t)r * 64 + j] = f2bf(o);
        }
    }
}

// ---------------------------------------------------------------------------
// Final gather: normalize u rows, logits, partial loss per block.
// ---------------------------------------------------------------------------
__global__ __launch_bounds__(256) void finalize_kernel(
    const float* __restrict__ Eu, const float* __restrict__ Ei,
    const int* __restrict__ uids, const int* __restrict__ iids,
    const float* __restrict__ labels,
    float* __restrict__ out, float* __restrict__ partials)
{
    int bidx = blockIdx.x * 256 + threadIdx.x;
    float part = 0.f;
    if (bidx < BQ) {
        const float4* u4 = (const float4*)(Eu + (size_t)uids[bidx] * 64);
        const float4* i4 = (const float4*)(Ei + (size_t)iids[bidx] * 64);
        float nrm = 0.f, dot = 0.f, regi = 0.f;
#pragma unroll
        for (int q = 0; q < 16; q++) {
            float4 u = u4[q], w = i4[q];
            nrm  += u.x * u.x + u.y * u.y + u.z * u.z + u.w * u.w;
            dot  += u.x * w.x + u.y * w.y + u.z * w.z + u.w * w.w;
            regi += w.x * w.x + w.y * w.y + w.z * w.z + w.w * w.w;
        }
        float inv   = 1.f / fmaxf(sqrtf(nrm), 1e-12f);
        float logit = dot * inv;
        out[1 + bidx] = logit;
        float regu = nrm * inv * inv;
        float y  = labels[bidx];
        float sp = fmaxf(logit, 0.f) + log1pf(expf(-fabsf(logit)));
        part = (sp - logit * y) * (1.f / (float)BQ) + 1e-6f * (regu + regi);
    }
    __shared__ float red[256];
    red[threadIdx.x] = part;
    __syncthreads();
    for (int s = 128; s > 0; s >>= 1) {
        if (threadIdx.x < s) red[threadIdx.x] += red[threadIdx.x + s];
        __syncthreads();
    }
    if (threadIdx.x == 0) partials[blockIdx.x] = red[0];
}

__global__ void reduce_loss(const float* __restrict__ partials, float* __restrict__ out)
{
    if (threadIdx.x == 0) {
        float s = 0.f;
        for (int i = 0; i < 32; i++) s += partials[i];
        out[0] = s;
    }
}

// ---------------------------------------------------------------------------
extern "C" void kernel_launch(void* const* d_in, const int* in_sizes, int n_in,
                              void* d_out, int out_size, void* d_ws, size_t ws_size,
                              hipStream_t stream)
{
    const int*   pos_rows = (const int*)d_in[0];
    const int*   pos_cols = (const int*)d_in[1];
    const float* pos_vals = (const float*)d_in[2];
    const int*   neg_rows = (const int*)d_in[3];
    const int*   neg_cols = (const int*)d_in[4];
    const float* neg_vals = (const float*)d_in[5];
    const int*   uids     = (const int*)d_in[6];
    const int*   iids     = (const int*)d_in[7];
    const float* labels   = (const float*)d_in[8];
    const float* E_u_0    = (const float*)d_in[9];
    const float* E_i_0    = (const float*)d_in[10];
    const float* W_u      = (const float*)d_in[11];
    const float* b_u      = (const float*)d_in[12];
    const float* W_i      = (const float*)d_in[13];
    const float* b_i      = (const float*)d_in[14];

    char* base = (char*)d_ws;
    size_t off = 0;
    auto alloc = [&](size_t bytes) { char* p = base + off; off += (bytes + 255) & ~(size_t)255; return p; };

    const size_t SU = (size_t)NU * DIMK;
    const size_t SI = (size_t)NI * DIMK;
    float* Ub[3]; float* Ib[3];
    for (int i = 0; i < 3; i++) Ub[i] = (float*)alloc(SU * 4);
    for (int i = 0; i < 3; i++) Ib[i] = (float*)alloc(SI * 4);
    int2* byR_p = (int2*)alloc((size_t)NNZP * 8);
    int2* byC_p = (int2*)alloc((size_t)NNZP * 8);
    int2* byR_n = (int2*)alloc((size_t)NNZN * 8);
    int2* byC_n = (int2*)alloc((size_t)NNZN * 8);
    unsigned short* Eu16 = (unsigned short*)alloc(SU * 2);
    unsigned short* Ei16 = (unsigned short*)alloc(SI * 2);
    int* ptr_pr = (int*)alloc((NU + 1) * 4);
    int* ptr_pc = (int*)alloc((NI + 1) * 4);
    int* ptr_nr = (int*)alloc((NU + 1) * 4);
    int* ptr_nc = (int*)alloc((NI + 1) * 4);
    int* cnt_all = (int*)alloc((size_t)(2 * NU + 2 * NI) * 4);  // contiguous
    int* cnt_pr = cnt_all;
    int* cnt_pc = cnt_all + NU;
    int* cnt_nr = cnt_all + NU + NI;
    int* cnt_nc = cnt_all + 2 * NU + NI;
    float* partials = (float*)alloc(32 * 4);

    // ---- CSR/CSC build ----
    hipMemsetAsync(cnt_all, 0, (size_t)(2 * NU + 2 * NI) * 4, stream);
    hist_all<<<(NNZP + NNZN + 255) / 256, 256, 0, stream>>>(
        pos_rows, pos_cols, neg_rows, neg_cols, cnt_pr, cnt_pc, cnt_nr, cnt_nc);
    exscan4<<<4, 1024, 0, stream>>>(cnt_pr, ptr_pr, NU, cnt_pc, ptr_pc, NI,
                                    cnt_nr, ptr_nr, NU, cnt_nc, ptr_nc, NI);
    scatter2<<<(NNZP + 255) / 256, 256, 0, stream>>>(
        pos_rows, pos_cols, pos_vals, NNZP, cnt_pr, cnt_pc, byR_p, byC_p);
    scatter2<<<(NNZN + 255) / 256, 256, 0, stream>>>(
        neg_rows, neg_cols, neg_vals, NNZN, cnt_nr, cnt_nc, byR_n, byC_n);

    to_bf16_init<<<(int)((SU + SI) / 4 + 255) / 256, 256, 0, stream>>>(E_u_0, E_i_0, Eu16, Ei16);

    // ---- 3 GCN layers ----
    const float* Eu_cur = E_u_0;
    const float* Ei_cur = E_i_0;
    for (int l = 0; l < 3; l++) {
        float* Zup = Ub[l];
        float* Zun = Ub[(l + 1) % 3];
        float* Zip = Ib[l];
        float* Zin = Ib[(l + 1) % 3];

        spmm_fused<<<(NU + NI + 3) / 4, 256, 0, stream>>>(
            ptr_pr, byR_p, ptr_nr, byR_n, ptr_pc, byC_p, ptr_nc, byC_n,
            Eu16, Ei16, Zup, Zun, Zip, Zin);

        linear_fuse2<<<NBU2 + NBI2, 256, 0, stream>>>(
            Eu_cur, Zup, Zun, W_u + (size_t)l * 5 * 64 * 64, b_u + (size_t)l * 5 * 64,
            Ei_cur, Zip, Zin, W_i + (size_t)l * 5 * 64 * 64, b_i + (size_t)l * 5 * 64,
            Eu16, Ei16);

        Eu_cur = Zup;
        Ei_cur = Zip;
    }

    finalize_kernel<<<BQ / 256, 256, 0, stream>>>(
        Eu_cur, Ei_cur, uids, iids, labels, (float*)d_out, partials);
    reduce_loss<<<1, 64, 0, stream>>>(partials, (float*)d_out);
}

// Round 6
// 1869.436 us; speedup vs baseline: 8.6516x; 1.1012x over previous
//
#include <hip/hip_runtime.h>
#include <cstdint>
#include <cstddef>

#define NU 100000
#define NI 50000
#define DIMK 64
#define NNZP 2000000
#define NNZN 1000000
#define BQ 8192
#define NBU2 3125       // NU/32 blocks for u-linear (exact)
#define NBI2 1563       // ceil(NI/32) blocks for i-linear
#define EPT 16          // edges per thread in scatter_xcd (4096/block)

typedef float v2f __attribute__((ext_vector_type(2)));

__device__ inline unsigned short f2bf(float f) {   // RNE fp32 -> bf16
    unsigned u = __float_as_uint(f);
    unsigned r = (u + 0x7fffu + ((u >> 16) & 1u)) >> 16;
    return (unsigned short)r;
}
__device__ inline float bf2f(unsigned short h) {
    return __uint_as_float(((unsigned)h) << 16);
}

// ---------------------------------------------------------------------------
// Fused histogram over pos+neg COO, both key directions.
// ---------------------------------------------------------------------------
__global__ __launch_bounds__(256) void hist_all(
    const int* __restrict__ pr, const int* __restrict__ pc,
    const int* __restrict__ nr, const int* __restrict__ nc,
    int* __restrict__ cnt_pr, int* __restrict__ cnt_pc,
    int* __restrict__ cnt_nr, int* __restrict__ cnt_nc)
{
    int i = blockIdx.x * 256 + threadIdx.x;
    if (i < NNZP) {
        atomicAdd(&cnt_pr[pr[i]], 1);
        atomicAdd(&cnt_pc[pc[i]], 1);
    } else if (i < NNZP + NNZN) {
        int j = i - NNZP;
        atomicAdd(&cnt_nr[nr[j]], 1);
        atomicAdd(&cnt_nc[nc[j]], 1);
    }
}

// ---------------------------------------------------------------------------
// Exclusive scan of 4 count arrays (one block each). cnt[] becomes cursor.
// ---------------------------------------------------------------------------
__global__ __launch_bounds__(1024) void exscan4(
    int* c0, int* p0, int n0, int* c1, int* p1, int n1,
    int* c2, int* p2, int n2, int* c3, int* p3, int n3)
{
    int* cnt; int* ptr; int n;
    switch (blockIdx.x) {
        case 0:  cnt = c0; ptr = p0; n = n0; break;
        case 1:  cnt = c1; ptr = p1; n = n1; break;
        case 2:  cnt = c2; ptr = p2; n = n2; break;
        default: cnt = c3; ptr = p3; n = n3; break;
    }
    __shared__ int ssum[1024];
    int t = threadIdx.x;
    int chunk = (n + 1023) >> 10;
    int start = t * chunk;
    int end   = min(start + chunk, n);
    int s = 0;
    for (int i = start; i < end; i++) s += cnt[i];
    ssum[t] = s;
    __syncthreads();
    for (int off = 1; off < 1024; off <<= 1) {
        int v = (t >= off) ? ssum[t - off] : 0;
        __syncthreads();
        ssum[t] += v;
        __syncthreads();
    }
    int base = (t > 0) ? ssum[t - 1] : 0;
    for (int i = start; i < end; i++) {
        int c = cnt[i];
        ptr[i] = base;
        cnt[i] = base;   // scatter cursor
        base += c;
    }
    if (t == 0) ptr[n] = ssum[1023];
}

// ---------------------------------------------------------------------------
// XCD-partitioned scatter. blockIdx round-robins across the 8 XCDs, so
// region = blockIdx&7 keeps ALL writers of any destination cache line on one
// XCD: lines assemble fully in that XCD's L2 and evict once (kills the 8x
// partial-line write amplification). Each XCD-class scans the whole COO
// stream (reads are LLC-served); only matching edges are stored.
// ---------------------------------------------------------------------------
__global__ __launch_bounds__(256) void scatter_xcd(
    const int* __restrict__ rows, const int* __restrict__ cols,
    const float* __restrict__ vals, int nnz,
    int* __restrict__ curR, int* __restrict__ curC,
    int2* __restrict__ byR, int2* __restrict__ byC)
{
    int xcd   = blockIdx.x & 7;
    int chunk = blockIdx.x >> 3;
    int rlo = (int)((long long)NU * xcd / 8),       rhi = (int)((long long)NU * (xcd + 1) / 8);
    int clo = (int)((long long)NI * xcd / 8),       chi = (int)((long long)NI * (xcd + 1) / 8);
    int base = chunk * (256 * EPT) + threadIdx.x;
#pragma unroll
    for (int it = 0; it < EPT; it++) {
        int i = base + it * 256;
        if (i >= nnz) break;
        int r = rows[i], c = cols[i];
        bool mr = (r >= rlo) & (r < rhi);
        bool mc = (c >= clo) & (c < chi);
        if (mr | mc) {
            int vb = __float_as_int(vals[i]);
            if (mr) { int p = atomicAdd(&curR[r], 1); byR[p] = make_int2(c, vb); }
            if (mc) { int q = atomicAdd(&curC[c], 1); byC[q] = make_int2(r, vb); }
        }
    }
}

// ---------------------------------------------------------------------------
// Initial fp32 -> bf16 copies of E_u_0 / E_i_0.
// ---------------------------------------------------------------------------
__global__ __launch_bounds__(256) void to_bf16_init(
    const float* __restrict__ Eu0, const float* __restrict__ Ei0,
    unsigned short* __restrict__ Eu16, unsigned short* __restrict__ Ei16)
{
    const size_t SU = (size_t)NU * DIMK, SI = (size_t)NI * DIMK;
    size_t i = ((size_t)blockIdx.x * 256 + threadIdx.x) * 4;
    if (i < SU) {
        float4 v = *(const float4*)(Eu0 + i);
        Eu16[i+0]=f2bf(v.x); Eu16[i+1]=f2bf(v.y); Eu16[i+2]=f2bf(v.z); Eu16[i+3]=f2bf(v.w);
    } else if (i < SU + SI) {
        size_t j = i - SU;
        float4 v = *(const float4*)(Ei0 + j);
        Ei16[j+0]=f2bf(v.x); Ei16[j+1]=f2bf(v.y); Ei16[j+2]=f2bf(v.z); Ei16[j+3]=f2bf(v.w);
    }
}

// ---------------------------------------------------------------------------
// Gather SpMM row accumulate. Lane k owns dim k. Edge (col,val) broadcast via
// v_readlane (SALU, no LDS pipe); 16 gather loads in flight per block.
// Inactive edge slots hold (0,0): col=0 is an in-bounds dummy row, val=0.
// ---------------------------------------------------------------------------
__device__ inline float row_gather(
    const int* __restrict__ ptr, const int2* __restrict__ edges,
    const unsigned short* __restrict__ X, int r, int lane)
{
    int beg = ptr[r], end = ptr[r + 1];
    float acc = 0.f;
    for (int e0 = beg; e0 < end; e0 += 64) {
        int2 ed = make_int2(0, 0);
        if (e0 + lane < end) ed = edges[e0 + lane];
        int nb = min(64, end - e0);
        for (int j = 0; j < nb; j += 16) {
            float x[16];
#pragma unroll
            for (int q = 0; q < 16; q++) {
                int col = __builtin_amdgcn_readlane(ed.x, j + q);
                x[q] = bf2f(X[(size_t)(unsigned)col * DIMK + lane]);
            }
#pragma unroll
            for (int q = 0; q < 16; q++) {
                float v = __uint_as_float(__builtin_amdgcn_readlane(ed.y, j + q));
                acc = fmaf(v, x[q], acc);
            }
        }
    }
    return acc;
}

__global__ __launch_bounds__(256) void spmm_fused(
    const int* __restrict__ ptr_pr, const int2* __restrict__ byR_p,
    const int* __restrict__ ptr_nr, const int2* __restrict__ byR_n,
    const int* __restrict__ ptr_pc, const int2* __restrict__ byC_p,
    const int* __restrict__ ptr_nc, const int2* __restrict__ byC_n,
    const unsigned short* __restrict__ Eu16, const unsigned short* __restrict__ Ei16,
    float* __restrict__ Zup, float* __restrict__ Zun,
    float* __restrict__ Zip, float* __restrict__ Zin)
{
    int wid  = (blockIdx.x * 256 + threadIdx.x) >> 6;
    int lane = threadIdx.x & 63;
    const int* pP; const int2* eP; const int* pN; const int2* eN;
    const unsigned short* X; float* Zp; float* Zn; int r;
    if (wid < NU) {
        r = wid; pP = ptr_pr; eP = byR_p; pN = ptr_nr; eN = byR_n;
        X = Ei16; Zp = Zup; Zn = Zun;
    } else if (wid < NU + NI) {
        r = wid - NU; pP = ptr_pc; eP = byC_p; pN = ptr_nc; eN = byC_n;
        X = Eu16; Zp = Zip; Zn = Zin;
    } else return;
    float ap = row_gather(pP, eP, X, r, lane);
    float an = row_gather(pN, eN, X, r, lane);
    Zp[(size_t)r * DIMK + lane] = ap;
    Zn[(size_t)r * DIMK + lane] = an;
}

// ---------------------------------------------------------------------------
// Fused 5-term linear + leaky-relu, both sides in one dispatch.
// Ws layout [t][kq][j][4] -> one ds_read_b128 per term per k4-step.
// 8 rows/wave, k-even/odd packed into float2 -> v_pk_fma_f32.
// ---------------------------------------------------------------------------
__global__ __launch_bounds__(256) void linear_fuse2(
    const float* __restrict__ Xu, float* __restrict__ Zup, const float* __restrict__ Zun,
    const float* __restrict__ Wu, const float* __restrict__ bu,
    const float* __restrict__ Xi, float* __restrict__ Zip, const float* __restrict__ Zin,
    const float* __restrict__ Wi, const float* __restrict__ bi,
    unsigned short* __restrict__ Eu16, unsigned short* __restrict__ Ei16)
{
    __shared__ float4 Ws4[5 * 16 * 64];  // [t][kq][j], float4 over q. 80 KiB
    int tid = threadIdx.x;

    const float* Xe; float* Zp; const float* Zn; const float* W; const float* b;
    unsigned short* E16; int N; int blk;
    if (blockIdx.x < NBU2) {
        Xe = Xu; Zp = Zup; Zn = Zun; W = Wu; b = bu; E16 = Eu16; N = NU; blk = blockIdx.x;
    } else {
        Xe = Xi; Zp = Zip; Zn = Zin; W = Wi; b = bi; E16 = Ei16; N = NI; blk = blockIdx.x - NBU2;
    }

    for (int g = tid; g < 5120; g += 256) {
        int j0 = g & 63;
        int kq = (g >> 6) & 15;
        int t  = g >> 10;
        float4 w = *(const float4*)(W + (size_t)t * 4096 + (size_t)j0 * 64 + kq * 4);
        Ws4[(t * 16 + kq) * 64 + j0] = w;
    }

    int j  = tid & 63;
    int wv = tid >> 6;
    float bsum = b[j] + b[64 + j] + b[128 + j] + b[192 + j] + b[256 + j];
    __syncthreads();

    int r0 = blk * 32 + wv * 8;
    int ro[8];
#pragma unroll
    for (int i = 0; i < 8; i++) {
        int r = r0 + i;
        ro[i] = ((r < N) ? r : (N - 1)) * 64;  // clamp loads; stores guarded
    }

    v2f acc[8];
#pragma unroll
    for (int i = 0; i < 8; i++) acc[i] = (v2f){0.f, 0.f};

    for (int kq = 0; kq < 16; kq++) {
        float4 w0 = Ws4[(0 * 16 + kq) * 64 + j];
        float4 w1 = Ws4[(1 * 16 + kq) * 64 + j];
        float4 w2 = Ws4[(2 * 16 + kq) * 64 + j];
        float4 w3 = Ws4[(3 * 16 + kq) * 64 + j];
        float4 w4 = Ws4[(4 * 16 + kq) * 64 + j];
        v2f w0l = {w0.x, w0.y}, w0h = {w0.z, w0.w};
        v2f w1l = {w1.x, w1.y}, w1h = {w1.z, w1.w};
        v2f w2l = {w2.x, w2.y}, w2h = {w2.z, w2.w};
        v2f w3l = {w3.x, w3.y}, w3h = {w3.z, w3.w};
        v2f w4l = {w4.x, w4.y}, w4h = {w4.z, w4.w};
        int ko = kq * 4;
#pragma unroll
        for (int i = 0; i < 8; i++) {
            float4 e4 = *(const float4*)(Xe + ro[i] + ko);
            float4 p4 = *(const float4*)(Zp + ro[i] + ko);
            float4 n4 = *(const float4*)(Zn + ro[i] + ko);
            v2f el = {e4.x, e4.y}, eh = {e4.z, e4.w};
            v2f pl = {p4.x, p4.y}, ph = {p4.z, p4.w};
            v2f nl = {n4.x, n4.y}, nh = {n4.z, n4.w};
            v2f a = acc[i];
            a = __builtin_elementwise_fma(el,      w0l, a);
            a = __builtin_elementwise_fma(eh,      w0h, a);
            a = __builtin_elementwise_fma(pl,      w1l, a);
            a = __builtin_elementwise_fma(ph,      w1h, a);
            a = __builtin_elementwise_fma(pl * el, w2l, a);
            a = __builtin_elementwise_fma(ph * eh, w2h, a);
            a = __builtin_elementwise_fma(nl,      w3l, a);
            a = __builtin_elementwise_fma(nh,      w3h, a);
            a = __builtin_elementwise_fma(nl * el, w4l, a);
            a = __builtin_elementwise_fma(nh * eh, w4h, a);
            acc[i] = a;
        }
    }

    __syncthreads();  // all reads of this block's Zp rows done before overwrite
#pragma unroll
    for (int i = 0; i < 8; i++) {
        int r = r0 + i;
        if (r < N) {
            float m = bsum + acc[i].x + acc[i].y;
            float o = (m > 0.f) ? m : 0.2f * m;
            Zp[(size_t)r * 64 + j] = o;
            E16[(size_t)r * 64 + j] = f2bf(o);
        }
    }
}

// ---------------------------------------------------------------------------
// Final gather: normalize u rows, logits, partial loss per block.
// ---------------------------------------------------------------------------
__global__ __launch_bounds__(256) void finalize_kernel(
    const float* __restrict__ Eu, const float* __restrict__ Ei,
    const int* __restrict__ uids, const int* __restrict__ iids,
    const float* __restrict__ labels,
    float* __restrict__ out, float* __restrict__ partials)
{
    int bidx = blockIdx.x * 256 + threadIdx.x;
    float part = 0.f;
    if (bidx < BQ) {
        const float4* u4 = (const float4*)(Eu + (size_t)uids[bidx] * 64);
        const float4* i4 = (const float4*)(Ei + (size_t)iids[bidx] * 64);
        float nrm = 0.f, dot = 0.f, regi = 0.f;
#pragma unroll
        for (int q = 0; q < 16; q++) {
            float4 u = u4[q], w = i4[q];
            nrm  += u.x * u.x + u.y * u.y + u.z * u.z + u.w * u.w;
            dot  += u.x * w.x + u.y * w.y + u.z * w.z + u.w * w.w;
            regi += w.x * w.x + w.y * w.y + w.z * w.z + w.w * w.w;
        }
        float inv   = 1.f / fmaxf(sqrtf(nrm), 1e-12f);
        float logit = dot * inv;
        out[1 + bidx] = logit;
        float regu = nrm * inv * inv;
        float y  = labels[bidx];
        float sp = fmaxf(logit, 0.f) + log1pf(expf(-fabsf(logit)));
        part = (sp - logit * y) * (1.f / (float)BQ) + 1e-6f * (regu + regi);
    }
    __shared__ float red[256];
    red[threadIdx.x] = part;
    __syncthreads();
    for (int s = 128; s > 0; s >>= 1) {
        if (threadIdx.x < s) red[threadIdx.x] += red[threadIdx.x + s];
        __syncthreads();
    }
    if (threadIdx.x == 0) partials[blockIdx.x] = red[0];
}

__global__ void reduce_loss(const float* __restrict__ partials, float* __restrict__ out)
{
    if (threadIdx.x == 0) {
        float s = 0.f;
        for (int i = 0; i < 32; i++) s += partials[i];
        out[0] = s;
    }
}

// ---------------------------------------------------------------------------
extern "C" void kernel_launch(void* const* d_in, const int* in_sizes, int n_in,
                              void* d_out, int out_size, void* d_ws, size_t ws_size,
                              hipStream_t stream)
{
    const int*   pos_rows = (const int*)d_in[0];
    const int*   pos_cols = (const int*)d_in[1];
    const float* pos_vals = (const float*)d_in[2];
    const int*   neg_rows = (const int*)d_in[3];
    const int*   neg_cols = (const int*)d_in[4];
    const float* neg_vals = (const float*)d_in[5];
    const int*   uids     = (const int*)d_in[6];
    const int*   iids     = (const int*)d_in[7];
    const float* labels   = (const float*)d_in[8];
    const float* E_u_0    = (const float*)d_in[9];
    const float* E_i_0    = (const float*)d_in[10];
    const float* W_u      = (const float*)d_in[11];
    const float* b_u      = (const float*)d_in[12];
    const float* W_i      = (const float*)d_in[13];
    const float* b_i      = (const float*)d_in[14];

    char* base = (char*)d_ws;
    size_t off = 0;
    auto alloc = [&](size_t bytes) { char* p = base + off; off += (bytes + 255) & ~(size_t)255; return p; };

    const size_t SU = (size_t)NU * DIMK;
    const size_t SI = (size_t)NI * DIMK;
    float* Ub[3]; float* Ib[3];
    for (int i = 0; i < 3; i++) Ub[i] = (float*)alloc(SU * 4);
    for (int i = 0; i < 3; i++) Ib[i] = (float*)alloc(SI * 4);
    int2* byR_p = (int2*)alloc((size_t)NNZP * 8);
    int2* byC_p = (int2*)alloc((size_t)NNZP * 8);
    int2* byR_n = (int2*)alloc((size_t)NNZN * 8);
    int2* byC_n = (int2*)alloc((size_t)NNZN * 8);
    unsigned short* Eu16 = (unsigned short*)alloc(SU * 2);
    unsigned short* Ei16 = (unsigned short*)alloc(SI * 2);
    int* ptr_pr = (int*)alloc((NU + 1) * 4);
    int* ptr_pc = (int*)alloc((NI + 1) * 4);
    int* ptr_nr = (int*)alloc((NU + 1) * 4);
    int* ptr_nc = (int*)alloc((NI + 1) * 4);
    int* cnt_all = (int*)alloc((size_t)(2 * NU + 2 * NI) * 4);  // contiguous
    int* cnt_pr = cnt_all;
    int* cnt_pc = cnt_all + NU;
    int* cnt_nr = cnt_all + NU + NI;
    int* cnt_nc = cnt_all + 2 * NU + NI;
    float* partials = (float*)alloc(32 * 4);

    // ---- CSR/CSC build ----
    hipMemsetAsync(cnt_all, 0, (size_t)(2 * NU + 2 * NI) * 4, stream);
    hist_all<<<(NNZP + NNZN + 255) / 256, 256, 0, stream>>>(
        pos_rows, pos_cols, neg_rows, neg_cols, cnt_pr, cnt_pc, cnt_nr, cnt_nc);
    exscan4<<<4, 1024, 0, stream>>>(cnt_pr, ptr_pr, NU, cnt_pc, ptr_pc, NI,
                                    cnt_nr, ptr_nr, NU, cnt_nc, ptr_nc, NI);
    {
        int chunks_p = (NNZP + 256 * EPT - 1) / (256 * EPT);
        int chunks_n = (NNZN + 256 * EPT - 1) / (256 * EPT);
        scatter_xcd<<<8 * chunks_p, 256, 0, stream>>>(
            pos_rows, pos_cols, pos_vals, NNZP, cnt_pr, cnt_pc, byR_p, byC_p);
        scatter_xcd<<<8 * chunks_n, 256, 0, stream>>>(
            neg_rows, neg_cols, neg_vals, NNZN, cnt_nr, cnt_nc, byR_n, byC_n);
    }

    to_bf16_init<<<(int)((SU + SI) / 4 + 255) / 256, 256, 0, stream>>>(E_u_0, E_i_0, Eu16, Ei16);

    // ---- 3 GCN layers ----
    const float* Eu_cur = E_u_0;
    const float* Ei_cur = E_i_0;
    for (int l = 0; l < 3; l++) {
        float* Zup = Ub[l];
        float* Zun = Ub[(l + 1) % 3];
        float* Zip = Ib[l];
        float* Zin = Ib[(l + 1) % 3];

        spmm_fused<<<(NU + NI + 3) / 4, 256, 0, stream>>>(
            ptr_pr, byR_p, ptr_nr, byR_n, ptr_pc, byC_p, ptr_nc, byC_n,
            Eu16, Ei16, Zup, Zun, Zip, Zin);

        linear_fuse2<<<NBU2 + NBI2, 256, 0, stream>>>(
            Eu_cur, Zup, Zun, W_u + (size_t)l * 5 * 64 * 64, b_u + (size_t)l * 5 * 64,
            Ei_cur, Zip, Zin, W_i + (size_t)l * 5 * 64 * 64, b_i + (size_t)l * 5 * 64,
            Eu16, Ei16);

        Eu_cur = Zup;
        Ei_cur = Zip;
    }

    finalize_kernel<<<BQ / 256, 256, 0, stream>>>(
        Eu_cur, Ei_cur, uids, iids, labels, (float*)d_out, partials);
    reduce_loss<<<1, 64, 0, stream>>>(partials, (float*)d_out);
}

// Round 7
// 1297.412 us; speedup vs baseline: 12.4660x; 1.4409x over previous
//
#include <hip/hip_runtime.h>
#include <cstdint>
#include <cstddef>

#define NU 100000
#define NI 50000
#define DIMK 64
#define NNZP 2000000
#define NNZN 1000000
#define BQ 8192
#define EPT 16          // edges per thread in scatter_xcd (4096/block)
#define NWU (NU / 16)   // 6250 u row-tiles (exact)
#define NWI (NI / 16)   // 3125 i row-tiles (exact)

typedef short s16x8 __attribute__((ext_vector_type(8)));
typedef float f32x4 __attribute__((ext_vector_type(4)));

__device__ inline unsigned short f2bf(float f) {   // RNE fp32 -> bf16
    unsigned u = __float_as_uint(f);
    unsigned r = (u + 0x7fffu + ((u >> 16) & 1u)) >> 16;
    return (unsigned short)r;
}
__device__ inline float bf2f(unsigned short h) {
    return __uint_as_float(((unsigned)h) << 16);
}

// elementwise bf16 product of two fragments (same (row,k) lane mapping)
__device__ inline s16x8 bfmul8(s16x8 a, s16x8 b) {
    s16x8 r;
#pragma unroll
    for (int q = 0; q < 8; q++) {
        float x = bf2f((unsigned short)a[q]);
        float y = bf2f((unsigned short)b[q]);
        r[q] = (short)f2bf(x * y);
    }
    return r;
}

// ---------------------------------------------------------------------------
// Fused histogram over pos+neg COO, both key directions.
// ---------------------------------------------------------------------------
__global__ __launch_bounds__(256) void hist_all(
    const int* __restrict__ pr, const int* __restrict__ pc,
    const int* __restrict__ nr, const int* __restrict__ nc,
    int* __restrict__ cnt_pr, int* __restrict__ cnt_pc,
    int* __restrict__ cnt_nr, int* __restrict__ cnt_nc)
{
    int i = blockIdx.x * 256 + threadIdx.x;
    if (i < NNZP) {
        atomicAdd(&cnt_pr[pr[i]], 1);
        atomicAdd(&cnt_pc[pc[i]], 1);
    } else if (i < NNZP + NNZN) {
        int j = i - NNZP;
        atomicAdd(&cnt_nr[nr[j]], 1);
        atomicAdd(&cnt_nc[nc[j]], 1);
    }
}

// ---------------------------------------------------------------------------
// Exclusive scan of 4 count arrays (one block each). cnt[] becomes cursor.
// ---------------------------------------------------------------------------
__global__ __launch_bounds__(1024) void exscan4(
    int* c0, int* p0, int n0, int* c1, int* p1, int n1,
    int* c2, int* p2, int n2, int* c3, int* p3, int n3)
{
    int* cnt; int* ptr; int n;
    switch (blockIdx.x) {
        case 0:  cnt = c0; ptr = p0; n = n0; break;
        case 1:  cnt = c1; ptr = p1; n = n1; break;
        case 2:  cnt = c2; ptr = p2; n = n2; break;
        default: cnt = c3; ptr = p3; n = n3; break;
    }
    __shared__ int ssum[1024];
    int t = threadIdx.x;
    int chunk = (n + 1023) >> 10;
    int start = t * chunk;
    int end   = min(start + chunk, n);
    int s = 0;
    for (int i = start; i < end; i++) s += cnt[i];
    ssum[t] = s;
    __syncthreads();
    for (int off = 1; off < 1024; off <<= 1) {
        int v = (t >= off) ? ssum[t - off] : 0;
        __syncthreads();
        ssum[t] += v;
        __syncthreads();
    }
    int base = (t > 0) ? ssum[t - 1] : 0;
    for (int i = start; i < end; i++) {
        int c = cnt[i];
        ptr[i] = base;
        cnt[i] = base;   // scatter cursor
        base += c;
    }
    if (t == 0) ptr[n] = ssum[1023];
}

// ---------------------------------------------------------------------------
// XCD-partitioned scatter (blockIdx&7 == XCD -> all writers of a dest line
// live on one XCD; lines assemble fully in its L2).
// ---------------------------------------------------------------------------
__global__ __launch_bounds__(256) void scatter_xcd(
    const int* __restrict__ rows, const int* __restrict__ cols,
    const float* __restrict__ vals, int nnz,
    int* __restrict__ curR, int* __restrict__ curC,
    int2* __restrict__ byR, int2* __restrict__ byC)
{
    int xcd   = blockIdx.x & 7;
    int chunk = blockIdx.x >> 3;
    int rlo = (int)((long long)NU * xcd / 8),       rhi = (int)((long long)NU * (xcd + 1) / 8);
    int clo = (int)((long long)NI * xcd / 8),       chi = (int)((long long)NI * (xcd + 1) / 8);
    int base = chunk * (256 * EPT) + threadIdx.x;
#pragma unroll
    for (int it = 0; it < EPT; it++) {
        int i = base + it * 256;
        if (i >= nnz) break;
        int r = rows[i], c = cols[i];
        bool mr = (r >= rlo) & (r < rhi);
        bool mc = (c >= clo) & (c < chi);
        if (mr | mc) {
            int vb = __float_as_int(vals[i]);
            if (mr) { int p = atomicAdd(&curR[r], 1); byR[p] = make_int2(c, vb); }
            if (mc) { int q = atomicAdd(&curC[c], 1); byC[q] = make_int2(r, vb); }
        }
    }
}

// ---------------------------------------------------------------------------
// Initial fp32 -> bf16 copies of E_u_0 / E_i_0.
// ---------------------------------------------------------------------------
__global__ __launch_bounds__(256) void to_bf16_init(
    const float* __restrict__ Eu0, const float* __restrict__ Ei0,
    unsigned short* __restrict__ Eu16, unsigned short* __restrict__ Ei16)
{
    const size_t SU = (size_t)NU * DIMK, SI = (size_t)NI * DIMK;
    size_t i = ((size_t)blockIdx.x * 256 + threadIdx.x) * 4;
    if (i < SU) {
        float4 v = *(const float4*)(Eu0 + i);
        Eu16[i+0]=f2bf(v.x); Eu16[i+1]=f2bf(v.y); Eu16[i+2]=f2bf(v.z); Eu16[i+3]=f2bf(v.w);
    } else if (i < SU + SI) {
        size_t j = i - SU;
        float4 v = *(const float4*)(Ei0 + j);
        Ei16[j+0]=f2bf(v.x); Ei16[j+1]=f2bf(v.y); Ei16[j+2]=f2bf(v.z); Ei16[j+3]=f2bf(v.w);
    }
}

// ---------------------------------------------------------------------------
// W fp32 -> bf16 (all 3 layers, both sides). 61440 floats per side.
// ---------------------------------------------------------------------------
__global__ __launch_bounds__(256) void w16_init(
    const float* __restrict__ Wu, const float* __restrict__ Wi,
    unsigned short* __restrict__ W16u, unsigned short* __restrict__ W16i)
{
    size_t i = ((size_t)blockIdx.x * 256 + threadIdx.x) * 4;
    if (i < 61440) {
        float4 v = *(const float4*)(Wu + i);
        W16u[i+0]=f2bf(v.x); W16u[i+1]=f2bf(v.y); W16u[i+2]=f2bf(v.z); W16u[i+3]=f2bf(v.w);
    } else if (i < 122880) {
        size_t j = i - 61440;
        float4 v = *(const float4*)(Wi + j);
        W16i[j+0]=f2bf(v.x); W16i[j+1]=f2bf(v.y); W16i[j+2]=f2bf(v.z); W16i[j+3]=f2bf(v.w);
    }
}

// ---------------------------------------------------------------------------
// Gather SpMM row accumulate. Lane k owns dim k. Edge (col,val) broadcast via
// v_readlane; 16 gather loads in flight. Outputs bf16.
// ---------------------------------------------------------------------------
__device__ inline float row_gather(
    const int* __restrict__ ptr, const int2* __restrict__ edges,
    const unsigned short* __restrict__ X, int r, int lane)
{
    int beg = ptr[r], end = ptr[r + 1];
    float acc = 0.f;
    for (int e0 = beg; e0 < end; e0 += 64) {
        int2 ed = make_int2(0, 0);
        if (e0 + lane < end) ed = edges[e0 + lane];
        int nb = min(64, end - e0);
        for (int j = 0; j < nb; j += 16) {
            float x[16];
#pragma unroll
            for (int q = 0; q < 16; q++) {
                int col = __builtin_amdgcn_readlane(ed.x, j + q);
                x[q] = bf2f(X[(size_t)(unsigned)col * DIMK + lane]);
            }
#pragma unroll
            for (int q = 0; q < 16; q++) {
                float v = __uint_as_float(__builtin_amdgcn_readlane(ed.y, j + q));
                acc = fmaf(v, x[q], acc);
            }
        }
    }
    return acc;
}

__global__ __launch_bounds__(256) void spmm_fused(
    const int* __restrict__ ptr_pr, const int2* __restrict__ byR_p,
    const int* __restrict__ ptr_nr, const int2* __restrict__ byR_n,
    const int* __restrict__ ptr_pc, const int2* __restrict__ byC_p,
    const int* __restrict__ ptr_nc, const int2* __restrict__ byC_n,
    const unsigned short* __restrict__ Eu16, const unsigned short* __restrict__ Ei16,
    unsigned short* __restrict__ Zup, unsigned short* __restrict__ Zun,
    unsigned short* __restrict__ Zip, unsigned short* __restrict__ Zin)
{
    int wid  = (blockIdx.x * 256 + threadIdx.x) >> 6;
    int lane = threadIdx.x & 63;
    const int* pP; const int2* eP; const int* pN; const int2* eN;
    const unsigned short* X; unsigned short* Zp; unsigned short* Zn; int r;
    if (wid < NU) {
        r = wid; pP = ptr_pr; eP = byR_p; pN = ptr_nr; eN = byR_n;
        X = Ei16; Zp = Zup; Zn = Zun;
    } else if (wid < NU + NI) {
        r = wid - NU; pP = ptr_pc; eP = byC_p; pN = ptr_nc; eN = byC_n;
        X = Eu16; Zp = Zip; Zn = Zin;
    } else return;
    float ap = row_gather(pP, eP, X, r, lane);
    float an = row_gather(pN, eN, X, r, lane);
    Zp[(size_t)r * DIMK + lane] = f2bf(ap);
    Zn[(size_t)r * DIMK + lane] = f2bf(an);
}

// ---------------------------------------------------------------------------
// MFMA 5-term linear + leaky-relu, both sides in one dispatch.
// Wave = 16-row stripe x 64 cols (4 col-tiles, 16x16x32, K=320 total).
// Product-term A-frags computed in-register (same (row,k) lane mapping).
// ---------------------------------------------------------------------------
__global__ __launch_bounds__(256) void linear_mfma(
    const unsigned short* __restrict__ Eu, const unsigned short* __restrict__ Zpu,
    const unsigned short* __restrict__ Znu, const unsigned short* __restrict__ Wu,
    const float* __restrict__ bu,
    const unsigned short* __restrict__ Ei, const unsigned short* __restrict__ Zpi,
    const unsigned short* __restrict__ Zni, const unsigned short* __restrict__ Wi,
    const float* __restrict__ bi,
    unsigned short* __restrict__ Ou, unsigned short* __restrict__ Oi,
    float* __restrict__ Fu, float* __restrict__ Fi)
{
    int w = blockIdx.x * 4 + (threadIdx.x >> 6);
    int lane = threadIdx.x & 63;
    const unsigned short *X, *Zp, *Zn, *W; const float* b;
    unsigned short* O16; float* O32; int rt;
    if (w < NWU)            { rt = w;       X=Eu; Zp=Zpu; Zn=Znu; W=Wu; b=bu; O16=Ou; O32=Fu; }
    else if (w < NWU + NWI) { rt = w - NWU; X=Ei; Zp=Zpi; Zn=Zni; W=Wi; b=bi; O16=Oi; O32=Fi; }
    else return;

    int arow = lane & 15, agrp = lane >> 4;
    size_t abase = ((size_t)rt * 16 + arow) * 64 + agrp * 8;

    s16x8 aE0 = *(const s16x8*)(X  + abase);
    s16x8 aE1 = *(const s16x8*)(X  + abase + 32);
    s16x8 aP0 = *(const s16x8*)(Zp + abase);
    s16x8 aP1 = *(const s16x8*)(Zp + abase + 32);
    s16x8 aN0 = *(const s16x8*)(Zn + abase);
    s16x8 aN1 = *(const s16x8*)(Zn + abase + 32);
    s16x8 aPE0 = bfmul8(aP0, aE0), aPE1 = bfmul8(aP1, aE1);
    s16x8 aNE0 = bfmul8(aN0, aE0), aNE1 = bfmul8(aN1, aE1);

    f32x4 acc[4];
#pragma unroll
    for (int ct = 0; ct < 4; ct++) {
        const unsigned short* Wb = W + (size_t)(ct * 16 + arow) * 64 + agrp * 8;
        f32x4 a = (f32x4){0.f, 0.f, 0.f, 0.f};
        a = __builtin_amdgcn_mfma_f32_16x16x32_bf16(aE0,  *(const s16x8*)(Wb +  0*4096 +  0), a, 0, 0, 0);
        a = __builtin_amdgcn_mfma_f32_16x16x32_bf16(aE1,  *(const s16x8*)(Wb +  0*4096 + 32), a, 0, 0, 0);
        a = __builtin_amdgcn_mfma_f32_16x16x32_bf16(aP0,  *(const s16x8*)(Wb +  1*4096 +  0), a, 0, 0, 0);
        a = __builtin_amdgcn_mfma_f32_16x16x32_bf16(aP1,  *(const s16x8*)(Wb +  1*4096 + 32), a, 0, 0, 0);
        a = __builtin_amdgcn_mfma_f32_16x16x32_bf16(aPE0, *(const s16x8*)(Wb +  2*4096 +  0), a, 0, 0, 0);
        a = __builtin_amdgcn_mfma_f32_16x16x32_bf16(aPE1, *(const s16x8*)(Wb +  2*4096 + 32), a, 0, 0, 0);
        a = __builtin_amdgcn_mfma_f32_16x16x32_bf16(aN0,  *(const s16x8*)(Wb +  3*4096 +  0), a, 0, 0, 0);
        a = __builtin_amdgcn_mfma_f32_16x16x32_bf16(aN1,  *(const s16x8*)(Wb +  3*4096 + 32), a, 0, 0, 0);
        a = __builtin_amdgcn_mfma_f32_16x16x32_bf16(aNE0, *(const s16x8*)(Wb +  4*4096 +  0), a, 0, 0, 0);
        a = __builtin_amdgcn_mfma_f32_16x16x32_bf16(aNE1, *(const s16x8*)(Wb +  4*4096 + 32), a, 0, 0, 0);
        acc[ct] = a;
    }

#pragma unroll
    for (int ct = 0; ct < 4; ct++) {
        int j = ct * 16 + arow;
        float bs = b[j] + b[64 + j] + b[128 + j] + b[192 + j] + b[256 + j];
#pragma unroll
        for (int q = 0; q < 4; q++) {
            size_t rr = (size_t)rt * 16 + agrp * 4 + q;
            float m = acc[ct][q] + bs;
            float o = (m > 0.f) ? m : 0.2f * m;
            O16[rr * 64 + j] = f2bf(o);
            if (O32) O32[rr * 64 + j] = o;
        }
    }
}

// ---------------------------------------------------------------------------
// Final gather: normalize u rows, logits, partial loss per block.
// ---------------------------------------------------------------------------
__global__ __launch_bounds__(256) void finalize_kernel(
    const float* __restrict__ Eu, const float* __restrict__ Ei,
    const int* __restrict__ uids, const int* __restrict__ iids,
    const float* __restrict__ labels,
    float* __restrict__ out, float* __restrict__ partials)
{
    int bidx = blockIdx.x * 256 + threadIdx.x;
    float part = 0.f;
    if (bidx < BQ) {
        const float4* u4 = (const float4*)(Eu + (size_t)uids[bidx] * 64);
        const float4* i4 = (const float4*)(Ei + (size_t)iids[bidx] * 64);
        float nrm = 0.f, dot = 0.f, regi = 0.f;
#pragma unroll
        for (int q = 0; q < 16; q++) {
            float4 u = u4[q], w = i4[q];
            nrm  += u.x * u.x + u.y * u.y + u.z * u.z + u.w * u.w;
            dot  += u.x * w.x + u.y * w.y + u.z * w.z + u.w * w.w;
            regi += w.x * w.x + w.y * w.y + w.z * w.z + w.w * w.w;
        }
        float inv   = 1.f / fmaxf(sqrtf(nrm), 1e-12f);
        float logit = dot * inv;
        out[1 + bidx] = logit;
        float regu = nrm * inv * inv;
        float y  = labels[bidx];
        float sp = fmaxf(logit, 0.f) + log1pf(expf(-fabsf(logit)));
        part = (sp - logit * y) * (1.f / (float)BQ) + 1e-6f * (regu + regi);
    }
    __shared__ float red[256];
    red[threadIdx.x] = part;
    __syncthreads();
    for (int s = 128; s > 0; s >>= 1) {
        if (threadIdx.x < s) red[threadIdx.x] += red[threadIdx.x + s];
        __syncthreads();
    }
    if (threadIdx.x == 0) partials[blockIdx.x] = red[0];
}

__global__ void reduce_loss(const float* __restrict__ partials, float* __restrict__ out)
{
    if (threadIdx.x == 0) {
        float s = 0.f;
        for (int i = 0; i < 32; i++) s += partials[i];
        out[0] = s;
    }
}

// ---------------------------------------------------------------------------
extern "C" void kernel_launch(void* const* d_in, const int* in_sizes, int n_in,
                              void* d_out, int out_size, void* d_ws, size_t ws_size,
                              hipStream_t stream)
{
    const int*   pos_rows = (const int*)d_in[0];
    const int*   pos_cols = (const int*)d_in[1];
    const float* pos_vals = (const float*)d_in[2];
    const int*   neg_rows = (const int*)d_in[3];
    const int*   neg_cols = (const int*)d_in[4];
    const float* neg_vals = (const float*)d_in[5];
    const int*   uids     = (const int*)d_in[6];
    const int*   iids     = (const int*)d_in[7];
    const float* labels   = (const float*)d_in[8];
    const float* E_u_0    = (const float*)d_in[9];
    const float* E_i_0    = (const float*)d_in[10];
    const float* W_u      = (const float*)d_in[11];
    const float* b_u      = (const float*)d_in[12];
    const float* W_i      = (const float*)d_in[13];
    const float* b_i      = (const float*)d_in[14];

    char* base = (char*)d_ws;
    size_t off = 0;
    auto alloc = [&](size_t bytes) { char* p = base + off; off += (bytes + 255) & ~(size_t)255; return p; };

    const size_t SU = (size_t)NU * DIMK;
    const size_t SI = (size_t)NI * DIMK;

    float* Eu32 = (float*)alloc(SU * 4);
    float* Ei32 = (float*)alloc(SI * 4);
    unsigned short* E16u[2] = { (unsigned short*)alloc(SU * 2), (unsigned short*)alloc(SU * 2) };
    unsigned short* E16i[2] = { (unsigned short*)alloc(SI * 2), (unsigned short*)alloc(SI * 2) };
    unsigned short* Zp16u = (unsigned short*)alloc(SU * 2);
    unsigned short* Zn16u = (unsigned short*)alloc(SU * 2);
    unsigned short* Zp16i = (unsigned short*)alloc(SI * 2);
    unsigned short* Zn16i = (unsigned short*)alloc(SI * 2);
    int2* byR_p = (int2*)alloc((size_t)NNZP * 8);
    int2* byC_p = (int2*)alloc((size_t)NNZP * 8);
    int2* byR_n = (int2*)alloc((size_t)NNZN * 8);
    int2* byC_n = (int2*)alloc((size_t)NNZN * 8);
    unsigned short* W16u = (unsigned short*)alloc(61440 * 2);
    unsigned short* W16i = (unsigned short*)alloc(61440 * 2);
    int* ptr_pr = (int*)alloc((NU + 1) * 4);
    int* ptr_pc = (int*)alloc((NI + 1) * 4);
    int* ptr_nr = (int*)alloc((NU + 1) * 4);
    int* ptr_nc = (int*)alloc((NI + 1) * 4);
    int* cnt_all = (int*)alloc((size_t)(2 * NU + 2 * NI) * 4);
    int* cnt_pr = cnt_all;
    int* cnt_pc = cnt_all + NU;
    int* cnt_nr = cnt_all + NU + NI;
    int* cnt_nc = cnt_all + 2 * NU + NI;
    float* partials = (float*)alloc(32 * 4);

    // ---- CSR/CSC build ----
    hipMemsetAsync(cnt_all, 0, (size_t)(2 * NU + 2 * NI) * 4, stream);
    hist_all<<<(NNZP + NNZN + 255) / 256, 256, 0, stream>>>(
        pos_rows, pos_cols, neg_rows, neg_cols, cnt_pr, cnt_pc, cnt_nr, cnt_nc);
    exscan4<<<4, 1024, 0, stream>>>(cnt_pr, ptr_pr, NU, cnt_pc, ptr_pc, NI,
                                    cnt_nr, ptr_nr, NU, cnt_nc, ptr_nc, NI);
    {
        int chunks_p = (NNZP + 256 * EPT - 1) / (256 * EPT);
        int chunks_n = (NNZN + 256 * EPT - 1) / (256 * EPT);
        scatter_xcd<<<8 * chunks_p, 256, 0, stream>>>(
            pos_rows, pos_cols, pos_vals, NNZP, cnt_pr, cnt_pc, byR_p, byC_p);
        scatter_xcd<<<8 * chunks_n, 256, 0, stream>>>(
            neg_rows, neg_cols, neg_vals, NNZN, cnt_nr, cnt_nc, byR_n, byC_n);
    }

    to_bf16_init<<<(int)((SU + SI) / 4 + 255) / 256, 256, 0, stream>>>(E_u_0, E_i_0, E16u[0], E16i[0]);
    w16_init<<<(122880 / 4 + 255) / 256, 256, 0, stream>>>(W_u, W_i, W16u, W16i);

    // ---- 3 GCN layers ----
    int cur = 0;
    for (int l = 0; l < 3; l++) {
        int nxt = cur ^ 1;
        spmm_fused<<<(NU + NI + 3) / 4, 256, 0, stream>>>(
            ptr_pr, byR_p, ptr_nr, byR_n, ptr_pc, byC_p, ptr_nc, byC_n,
            E16u[cur], E16i[cur], Zp16u, Zn16u, Zp16i, Zn16i);

        linear_mfma<<<(NWU + NWI + 3) / 4, 256, 0, stream>>>(
            E16u[cur], Zp16u, Zn16u, W16u + (size_t)l * 20480, b_u + (size_t)l * 320,
            E16i[cur], Zp16i, Zn16i, W16i + (size_t)l * 20480, b_i + (size_t)l * 320,
            E16u[nxt], E16i[nxt],
            (l == 2) ? Eu32 : (float*)nullptr, (l == 2) ? Ei32 : (float*)nullptr);

        cur = nxt;
    }

    finalize_kernel<<<BQ / 256, 256, 0, stream>>>(
        Eu32, Ei32, uids, iids, labels, (float*)d_out, partials);
    reduce_loss<<<1, 64, 0, stream>>>(partials, (float*)d_out);
}